// Round 6
// baseline (385.932 us; speedup 1.0000x reference)
//
#include <hip/hip_runtime.h>
#include <stdint.h>
#include <math.h>

#define B_   4
#define T_   4096
#define BT_  16384
#define HID  2048
#define ED   256
#define HD   32
#define NH   8
#define K3   768   // packed K for split-precision key GEMM

typedef unsigned short u16;
typedef __attribute__((ext_vector_type(8))) short short8;
typedef __attribute__((ext_vector_type(4))) float f32x4;
typedef __attribute__((ext_vector_type(16))) float f32x16;

typedef __attribute__((address_space(1))) void gvoid;
typedef __attribute__((address_space(3))) void lvoid;

__device__ __forceinline__ float bf2f(u16 h) {
    return __uint_as_float(((uint32_t)h) << 16);
}
__device__ __forceinline__ u16 f2bf(float f) {
    uint32_t u = __float_as_uint(f);
    u += 0x7FFFu + ((u >> 16) & 1u);   // round-to-nearest-even
    return (u16)(u >> 16);
}
__device__ __forceinline__ void gld_lds16(const void* g, void* l) {
    __builtin_amdgcn_global_load_lds((gvoid*)(uintptr_t)g, (lvoid*)(uintptr_t)l, 16, 0, 0);
}
__device__ __forceinline__ void BAR() {
    asm volatile("" ::: "memory");
    __builtin_amdgcn_s_barrier();
    asm volatile("" ::: "memory");
}

// ---- Wk -> packed [hi | lo | hi] rows of 768 (pairs with A3 = [hi | hi | lo]) ----
__global__ void k_cvt_wk3(const float* __restrict__ in, u16* __restrict__ out) {
    int i = blockIdx.x * 256 + threadIdx.x;   // over HID*ED
    int n = i >> 8, c = i & 255;
    float f = in[i];
    u16 h = f2bf(f);
    out[(size_t)n * K3 + c]       = h;
    out[(size_t)n * K3 + 256 + c] = f2bf(f - bf2f(h));
    out[(size_t)n * K3 + 512 + c] = h;
}

// ---- pack B (NxK row-major) into MFMA 32x32x16 fragment order ----
// frag f = nt*(K/16)+kt holds lane l: B[nt*32+(l&31)][kt*16+(l>>5)*8 .. +8]
__global__ void k_packB_f32(const float* __restrict__ src, u16* __restrict__ dst, int N, int Kp) {
    int gid = blockIdx.x * 256 + threadIdx.x;      // over N*Kp/8
    int f = gid >> 6, l = gid & 63;
    int kt16 = Kp >> 4;
    int nt = f / kt16, kt = f - nt * kt16;
    int n = nt * 32 + (l & 31), k = kt * 16 + (l >> 5) * 8;
    const float* s = src + (size_t)n * Kp + k;
    u16 tmp[8];
#pragma unroll
    for (int j = 0; j < 8; ++j) tmp[j] = f2bf(s[j]);
    *(short8*)(dst + (size_t)f * 512 + l * 8) = *(const short8*)tmp;
}
__global__ void k_packB_u16(const u16* __restrict__ src, u16* __restrict__ dst, int N, int Kp) {
    int gid = blockIdx.x * 256 + threadIdx.x;
    int f = gid >> 6, l = gid & 63;
    int kt16 = Kp >> 4;
    int nt = f / kt16, kt = f - nt * kt16;
    int n = nt * 32 + (l & 31), k = kt * 16 + (l >> 5) * 8;
    *(short8*)(dst + (size_t)f * 512 + l * 8) = *(const short8*)(src + (size_t)n * Kp + k);
}

// ---------------- hash-embedding gather (f32) ----------------
__global__ void k_gather(const int* __restrict__ hashes, const int* __restrict__ offs,
                         const float* __restrict__ tab, float* __restrict__ E) {
    const int bt = blockIdx.x;
    const int tid = threadIdx.x;          // 256 = 8 heads x 32 dims
    const int head = tid >> 5, d = tid & 31;
    const int row = hashes[bt * NH + head] + offs[head];
    E[(size_t)bt * ED + tid] = tab[(size_t)row * HD + d];
}

// ---- conv + LN + silu + residual; writes A3 row = [e_hi | e_hi | e_lo] (768) ----
__global__ void k_conv(const float* __restrict__ E, const float* __restrict__ w,
                       const float* __restrict__ lng, const float* __restrict__ lnb,
                       u16* __restrict__ a3) {
    const int bt = blockIdx.x;
    const int b = bt >> 12;               // T_ = 4096
    const int t = bt & 4095;
    const int ch = threadIdx.x;           // 256
    float c = 0.f;
#pragma unroll
    for (int k = 0; k < 4; ++k) {
        int tt = t - 9 + 3 * k;           // taps at t-9, t-6, t-3, t
        if (tt >= 0)
            c += w[ch * 4 + k] * E[((size_t)(b * T_ + tt)) * ED + ch];
    }
    float s = c, s2 = c * c;
#pragma unroll
    for (int o = 32; o; o >>= 1) { s += __shfl_xor(s, o); s2 += __shfl_xor(s2, o); }
    __shared__ float red[8];
    const int wid = ch >> 6, lane = ch & 63;
    if (!lane) { red[wid] = s; red[4 + wid] = s2; }
    __syncthreads();
    s  = red[0] + red[1] + red[2] + red[3];
    s2 = red[4] + red[5] + red[6] + red[7];
    const float mean = s * (1.f / 256.f);
    const float var  = s2 * (1.f / 256.f) - mean * mean;
    float ln = (c - mean) * rsqrtf(var + 1e-5f) * lng[ch] + lnb[ch];
    float si = ln / (1.f + expf(-ln));    // silu
    float ev = E[(size_t)bt * ED + ch] + si;
    u16 h = f2bf(ev);
    a3[(size_t)bt * K3 + ch]       = h;
    a3[(size_t)bt * K3 + 256 + ch] = h;
    a3[(size_t)bt * K3 + 512 + ch] = f2bf(ev - bf2f(h));
}

// ---------------- per-row: q=LN(x), kln=LN(key f32), g, gamma (float4 loads) ----------------
__global__ void k_gamma(const float* __restrict__ x, const float* __restrict__ key,
                        const float* __restrict__ gk, const float* __restrict__ bk,
                        const float* __restrict__ gq, const float* __restrict__ bq,
                        float* __restrict__ gamma) {
    const int m = blockIdx.x;
    const int tid = threadIdx.x;          // 256 thr, 2 float4 each = 2048 floats
    const f32x4* xr = (const f32x4*)(x + (size_t)m * HID);
    const f32x4* kr = (const f32x4*)(key + (size_t)m * HID);
    f32x4 xs[2], ks[2];
    float sx = 0.f, sx2 = 0.f, sk = 0.f, sk2 = 0.f;
#pragma unroll
    for (int i = 0; i < 2; ++i) {
        f32x4 xv = xr[tid + i * 256]; xs[i] = xv;
        f32x4 kv = kr[tid + i * 256]; ks[i] = kv;
#pragma unroll
        for (int c = 0; c < 4; ++c) {
            sx += xv[c]; sx2 += xv[c] * xv[c];
            sk += kv[c]; sk2 += kv[c] * kv[c];
        }
    }
#pragma unroll
    for (int o = 32; o; o >>= 1) {
        sx += __shfl_xor(sx, o); sx2 += __shfl_xor(sx2, o);
        sk += __shfl_xor(sk, o); sk2 += __shfl_xor(sk2, o);
    }
    __shared__ float red[16];
    const int wid = tid >> 6, lane = tid & 63;
    if (!lane) { red[wid] = sx; red[4 + wid] = sx2; red[8 + wid] = sk; red[12 + wid] = sk2; }
    __syncthreads();
    sx  = red[0] + red[1] + red[2] + red[3];
    sx2 = red[4] + red[5] + red[6] + red[7];
    sk  = red[8] + red[9] + red[10] + red[11];
    sk2 = red[12] + red[13] + red[14] + red[15];
    const float inv = 1.f / (float)HID;
    const float mx = sx * inv, vx = sx2 * inv - mx * mx;
    const float mk = sk * inv, vk = sk2 * inv - mk * mk;
    const float rx = rsqrtf(vx + 1e-5f), rk = rsqrtf(vk + 1e-5f);
    float dot = 0.f;
#pragma unroll
    for (int i = 0; i < 2; ++i) {
        const int v4 = tid + i * 256;
        f32x4 g4 = ((const f32x4*)gq)[v4];
        f32x4 b4 = ((const f32x4*)bq)[v4];
        f32x4 gk4 = ((const f32x4*)gk)[v4];
        f32x4 bk4 = ((const f32x4*)bk)[v4];
#pragma unroll
        for (int c = 0; c < 4; ++c) {
            float q  = (xs[i][c] - mx) * rx * g4[c] + b4[c];
            float kl = (ks[i][c] - mk) * rk * gk4[c] + bk4[c];
            dot += q * kl;
        }
    }
#pragma unroll
    for (int o = 32; o; o >>= 1) dot += __shfl_xor(dot, o);
    __syncthreads();
    if (!lane) red[wid] = dot;
    __syncthreads();
    if (tid == 0) {
        float gd = (red[0] + red[1] + red[2] + red[3]) * 0.022097086912079608f; // 1/sqrt(2048)
        float sg = (gd > 0.f) ? 1.f : ((gd < 0.f) ? -1.f : 0.f);
        float sv = sqrtf(fmaxf(fabsf(gd), 1e-6f)) * sg;
        gamma[m] = 1.f / (1.f + expf(-sv));
    }
}

// ============ 256x256 GEMM, 32x32x16 MFMA, A-only LDS, B regs from packed global ============
// C[m,n] = (rowscale[m]?) * sum_k A[m,k]*B[n,k]; A MxK bf16 (row stride LDA),
// Bp = fragment-packed B. 512 thr = 8 waves (2M x 4N), per-wave out 128x64
// (4 m-tiles x 2 n-tiles of 32x32, acc = 128 f32). LDS 64 KiB = A dbuf only
// (256x64x2B per buf), XOR-swizzle on 16B slots: slot' = slot ^ (row&7), applied
// on stage-source col and ds_read (involution). B frags double-buffered in regs.
// Per iter t: issue B(t+1)->reg set[t+1&1]; vmcnt(12) (drains A(t) staged 2 iters
// ago + B(t) issued 1 iter ago; leaves A(t+1)+B(t+1)=12 in flight); BAR; compute
// (16 ds_read_b128 + 32 MFMA); BAR; stage A(t+2) into buf[t&1]. Never vmcnt(0)
// in steady state.
template <int K, int LDA, bool SCALE, bool OUTBF16>
__global__ __launch_bounds__(512, 2)
void gemm32(const u16* __restrict__ A, const u16* __restrict__ Bp,
            const float* __restrict__ rowscale, void* __restrict__ Cout,
            int M, int N) {
    extern __shared__ char smem[];
    constexpr int NK = K >> 6;     // K-tiles (even for all our shapes)
    constexpr int KF = K >> 4;     // k-frags per n-tile row
    const int tid = threadIdx.x, wid = tid >> 6, lane = tid & 63;
    const int l31 = lane & 31, hl = lane >> 5, l7 = lane & 7;
    const int wr = wid >> 2, wc = wid & 3;

    // XCD-aware swizzle (nwg % 8 == 0 here)
    const int tiles_m = M >> 8;
    const int nwg = gridDim.x, cpx = nwg >> 3, id = blockIdx.x;
    const int swz = (id & 7) * cpx + (id >> 3);
    const int mblk = (swz % tiles_m) << 8;
    const int nblk = (swz / tiles_m) << 8;

    f32x16 acc[4][2];
#pragma unroll
    for (int i = 0; i < 4; ++i)
#pragma unroll
        for (int j = 0; j < 2; ++j)
#pragma unroll
            for (int r = 0; r < 16; ++r) acc[i][j][r] = 0.f;

    // A staging: thread stages 4x16B; linear LDS o = i*8192 + tid*16 ->
    // row = (tid>>3)+i*64, slot = tid&7; source col-slot pre-swizzled.
    const int srow = tid >> 3;
    const int scol = (((tid & 7) ^ ((tid >> 3) & 7)) << 3);   // u16 units
    const u16* aR0 = A + (size_t)(mblk + srow) * LDA + scol;

    // B fragment base for this wave (lane's 16B within each 1KB frag)
    const u16* bbase = Bp + ((size_t)((nblk >> 5) + wc * 2) * KF) * 512 + lane * 8;

    // A ds_read: row = wr*128 + mt*32 + l31; 16B slot = (ks*2 + hl) ^ l7
    const int arow_b = (wr * 128 + l31) * 128;
    const int koff0 = (((0 + hl) ^ l7) << 4);
    const int koff1 = (((2 + hl) ^ l7) << 4);
    const int koff2 = (((4 + hl) ^ l7) << 4);
    const int koff3 = (((6 + hl) ^ l7) << 4);

    short8 bfr0[8], bfr1[8], arE[4], arO[4];

#define STAGE_A(tt) do {                                                          \
        char* d_ = smem + (((tt) & 1) * 32768) + wid * 1024;                      \
        const u16* s_ = aR0 + (size_t)(tt) * 64;                                  \
        gld_lds16(s_, d_);                                                        \
        gld_lds16(s_ + (size_t)64  * LDA, d_ + 8192);                             \
        gld_lds16(s_ + (size_t)128 * LDA, d_ + 16384);                            \
        gld_lds16(s_ + (size_t)192 * LDA, d_ + 24576); } while (0)
#define LOADB(S, tt) do {                                                         \
        _Pragma("unroll") for (int nt = 0; nt < 2; ++nt)                          \
        _Pragma("unroll") for (int ks = 0; ks < 4; ++ks)                          \
            bfr##S[nt * 4 + ks] =                                                 \
                *(const short8*)(bbase + ((size_t)nt * KF + (tt) * 4 + ks) * 512);\
    } while (0)
#define LDSLICE(dst, PAR, koff) do {                                              \
        _Pragma("unroll") for (int mt = 0; mt < 4; ++mt)                          \
            dst[mt] = *(const short8*)(smem + (PAR) * 32768 + arow_b              \
                                       + mt * 4096 + (koff)); } while (0)
#define MFMA8(src, S, ks) do {                                                    \
        _Pragma("unroll") for (int mt = 0; mt < 4; ++mt)                          \
        _Pragma("unroll") for (int nt = 0; nt < 2; ++nt)                          \
            acc[mt][nt] = __builtin_amdgcn_mfma_f32_32x32x16_bf16(                \
                src[mt], bfr##S[nt * 4 + ks], acc[mt][nt], 0, 0, 0); } while (0)
#define MMQ(PAR) do { __builtin_amdgcn_s_setprio(1);                              \
        LDSLICE(arE, PAR, koff0);                                                 \
        LDSLICE(arO, PAR, koff1); MFMA8(arE, PAR, 0);                             \
        LDSLICE(arE, PAR, koff2); MFMA8(arO, PAR, 1);                             \
        LDSLICE(arO, PAR, koff3); MFMA8(arE, PAR, 2);                             \
        MFMA8(arO, PAR, 3);                                                       \
        __builtin_amdgcn_s_setprio(0); } while (0)
#define ITER(tt, PAR, OTH) do {                                                   \
        if ((tt) + 1 < NK) {                                                      \
            LOADB(OTH, (tt) + 1);                                                 \
            asm volatile("s_waitcnt vmcnt(12)" ::: "memory");                     \
        } else {                                                                  \
            asm volatile("s_waitcnt vmcnt(0)" ::: "memory");                      \
        }                                                                         \
        BAR();                                                                    \
        MMQ(PAR);                                                                 \
        BAR();                                                                    \
        if ((tt) + 2 < NK) STAGE_A((tt) + 2); } while (0)

    // prologue: A(0), B(0), A(1) in flight (16 ops)
    STAGE_A(0);
    LOADB(0, 0);
    STAGE_A(1);

    for (int t = 0; t < NK; t += 2) {
        ITER(t, 0, 1);
        ITER(t + 1, 1, 0);
    }
#undef STAGE_A
#undef LOADB
#undef LDSLICE
#undef MFMA8
#undef MMQ
#undef ITER

    // epilogue: 32x32 C/D layout: row=(r&3)+8*(r>>2)+4*hl, col=l31 (m74/m101)
#pragma unroll
    for (int mt = 0; mt < 4; ++mt) {
#pragma unroll
        for (int r = 0; r < 16; ++r) {
            const int m = mblk + wr * 128 + mt * 32 + (r & 3) + 8 * (r >> 2) + 4 * hl;
            const float sc = SCALE ? rowscale[m] : 1.0f;
#pragma unroll
            for (int nt = 0; nt < 2; ++nt) {
                const int n = nblk + wc * 64 + nt * 32 + l31;
                const float v = acc[mt][nt][r] * sc;
                if (OUTBF16) ((u16*)Cout)[(size_t)m * N + n] = f2bf(v);
                else         ((float*)Cout)[(size_t)m * N + n] = v;
            }
        }
    }
}

extern "C" void kernel_launch(void* const* d_in, const int* in_sizes, int n_in,
                              void* d_out, int out_size, void* d_ws, size_t ws_size,
                              hipStream_t stream) {
    const float* x      = (const float*)d_in[0];
    const int*   hashes = (const int*)d_in[1];
    const int*   offs   = (const int*)d_in[2];
    const float* emb    = (const float*)d_in[3];
    const float* conv_w = (const float*)d_in[4];
    const float* lncg   = (const float*)d_in[5];
    const float* lncb   = (const float*)d_in[6];
    const float* Wk     = (const float*)d_in[7];
    const float* Wv     = (const float*)d_in[8];
    const float* Wo     = (const float*)d_in[9];
    const float* lnkg   = (const float*)d_in[10];
    const float* lnkb   = (const float*)d_in[11];
    const float* lnqg   = (const float*)d_in[12];
    const float* lnqb   = (const float*)d_in[13];

    // ws layout (~175 MB): E (16.8) and value (67) alias the key region (134).
    char* p = (char*)d_ws;
    float* key   = (float*)p;
    float* E     = (float*)p;
    u16*   value = (u16*)p;  p += (size_t)BT_ * HID * 4;
    u16*   A3    = (u16*)p;  p += (size_t)BT_ * K3 * 2;
    u16*   Wk3   = (u16*)p;  p += (size_t)HID * K3 * 2;
    u16*   Wk3p  = (u16*)p;  p += (size_t)HID * K3 * 2;
    u16*   Wvp   = (u16*)p;  p += (size_t)HID * ED * 2;
    u16*   Wop   = (u16*)p;  p += (size_t)HID * HID * 2;
    float* gamma = (float*)p; p += (size_t)BT_ * 4;

    hipFuncSetAttribute((const void*)gemm32<K3, K3, false, false>,
                        hipFuncAttributeMaxDynamicSharedMemorySize, 65536);
    hipFuncSetAttribute((const void*)gemm32<ED, K3, true, true>,
                        hipFuncAttributeMaxDynamicSharedMemorySize, 65536);
    hipFuncSetAttribute((const void*)gemm32<HID, HID, false, false>,
                        hipFuncAttributeMaxDynamicSharedMemorySize, 65536);

    k_cvt_wk3<<<(HID * ED) / 256, 256, 0, stream>>>(Wk, Wk3);
    k_packB_u16<<<(HID * K3 / 8) / 256, 256, 0, stream>>>(Wk3, Wk3p, HID, K3);
    k_packB_f32<<<(HID * ED / 8) / 256, 256, 0, stream>>>(Wv, Wvp, HID, ED);
    k_packB_f32<<<(HID * HID / 8) / 256, 256, 0, stream>>>(Wo, Wop, HID, HID);
    k_gather<<<BT_, 256, 0, stream>>>(hashes, offs, emb, E);
    k_conv<<<BT_, 256, 0, stream>>>(E, conv_w, lncg, lncb, A3);

    const dim3 grid((BT_ / 256) * (HID / 256));   // 512, %8==0
    // key = [ehi|ehi|elo] @ [Wkhi|Wklo|Wkhi]^T  (K'=768) -> f32
    gemm32<K3, K3, false, false><<<grid, 512, 65536, stream>>>(
        A3, Wk3p, nullptr, key, BT_, HID);
    k_gamma<<<BT_, 256, 0, stream>>>(x, key, lnkg, lnkb, lnqg, lnqb, gamma);
    // value = gamma * (ehi @ Wv^T)  (K=256) -> bf16 (overwrites dead key)
    gemm32<ED, K3, true, true><<<grid, 512, 65536, stream>>>(
        A3, Wvp, gamma, value, BT_, HID);
    // out = value @ Wo^T  (K=2048) -> f32
    gemm32<HID, HID, false, false><<<grid, 512, 65536, stream>>>(
        value, Wop, nullptr, d_out, BT_, HID);
}

// Round 7
// 359.022 us; speedup vs baseline: 1.0750x; 1.0750x over previous
//
#include <hip/hip_runtime.h>
#include <stdint.h>
#include <math.h>

#define B_   4
#define T_   4096
#define BT_  16384
#define HID  2048
#define ED   256
#define HD   32
#define NH   8
#define K3   768   // packed K for split-precision key GEMM

typedef unsigned short u16;
typedef __attribute__((ext_vector_type(8))) short short8;
typedef __attribute__((ext_vector_type(4))) float f32x4;

typedef __attribute__((address_space(1))) void gvoid;
typedef __attribute__((address_space(3))) void lvoid;

__device__ __forceinline__ float bf2f(u16 h) {
    return __uint_as_float(((uint32_t)h) << 16);
}
__device__ __forceinline__ u16 f2bf(float f) {
    uint32_t u = __float_as_uint(f);
    u += 0x7FFFu + ((u >> 16) & 1u);   // round-to-nearest-even
    return (u16)(u >> 16);
}
__device__ __forceinline__ void gld_lds16(const void* g, void* l) {
    __builtin_amdgcn_global_load_lds((gvoid*)(uintptr_t)g, (lvoid*)(uintptr_t)l, 16, 0, 0);
}
__device__ __forceinline__ void BAR() {
    asm volatile("" ::: "memory");
    __builtin_amdgcn_s_barrier();
    asm volatile("" ::: "memory");
}

// ---------------- f32 -> bf16 convert ----------------
__global__ void k_cvt(const float* __restrict__ in, u16* __restrict__ out, int n) {
    int i = blockIdx.x * 256 + threadIdx.x;
    if (i < n) out[i] = f2bf(in[i]);
}

// ---- Wk -> packed [hi | lo | hi] rows of 768 (pairs with A3 = [hi | hi | lo]) ----
__global__ void k_cvt_wk3(const float* __restrict__ in, u16* __restrict__ out) {
    int i = blockIdx.x * 256 + threadIdx.x;   // over HID*ED
    int n = i >> 8, c = i & 255;
    float f = in[i];
    u16 h = f2bf(f);
    out[(size_t)n * K3 + c]       = h;
    out[(size_t)n * K3 + 256 + c] = f2bf(f - bf2f(h));
    out[(size_t)n * K3 + 512 + c] = h;
}

// ---------------- hash-embedding gather (f32) ----------------
__global__ void k_gather(const int* __restrict__ hashes, const int* __restrict__ offs,
                         const float* __restrict__ tab, float* __restrict__ E) {
    const int bt = blockIdx.x;
    const int tid = threadIdx.x;          // 256 = 8 heads x 32 dims
    const int head = tid >> 5, d = tid & 31;
    const int row = hashes[bt * NH + head] + offs[head];
    E[(size_t)bt * ED + tid] = tab[(size_t)row * HD + d];
}

// ---- conv + LN + silu + residual; writes A3 row = [e_hi | e_hi | e_lo] (768) ----
__global__ void k_conv(const float* __restrict__ E, const float* __restrict__ w,
                       const float* __restrict__ lng, const float* __restrict__ lnb,
                       u16* __restrict__ a3) {
    const int bt = blockIdx.x;
    const int b = bt >> 12;               // T_ = 4096
    const int t = bt & 4095;
    const int ch = threadIdx.x;           // 256
    float c = 0.f;
#pragma unroll
    for (int k = 0; k < 4; ++k) {
        int tt = t - 9 + 3 * k;           // taps at t-9, t-6, t-3, t
        if (tt >= 0)
            c += w[ch * 4 + k] * E[((size_t)(b * T_ + tt)) * ED + ch];
    }
    float s = c, s2 = c * c;
#pragma unroll
    for (int o = 32; o; o >>= 1) { s += __shfl_xor(s, o); s2 += __shfl_xor(s2, o); }
    __shared__ float red[8];
    const int wid = ch >> 6, lane = ch & 63;
    if (!lane) { red[wid] = s; red[4 + wid] = s2; }
    __syncthreads();
    s  = red[0] + red[1] + red[2] + red[3];
    s2 = red[4] + red[5] + red[6] + red[7];
    const float mean = s * (1.f / 256.f);
    const float var  = s2 * (1.f / 256.f) - mean * mean;
    float ln = (c - mean) * rsqrtf(var + 1e-5f) * lng[ch] + lnb[ch];
    float si = ln / (1.f + expf(-ln));    // silu
    float ev = E[(size_t)bt * ED + ch] + si;
    u16 h = f2bf(ev);
    a3[(size_t)bt * K3 + ch]       = h;
    a3[(size_t)bt * K3 + 256 + ch] = h;
    a3[(size_t)bt * K3 + 512 + ch] = f2bf(ev - bf2f(h));
}

// ---------------- per-row: q=LN(x), kln=LN(key f32), g, gamma (float4 loads) ----------------
__global__ void k_gamma(const float* __restrict__ x, const float* __restrict__ key,
                        const float* __restrict__ gk, const float* __restrict__ bk,
                        const float* __restrict__ gq, const float* __restrict__ bq,
                        float* __restrict__ gamma) {
    const int m = blockIdx.x;
    const int tid = threadIdx.x;          // 256 thr, 2 float4 each = 2048 floats
    const f32x4* xr = (const f32x4*)(x + (size_t)m * HID);
    const f32x4* kr = (const f32x4*)(key + (size_t)m * HID);
    f32x4 xs[2], ks[2];
    float sx = 0.f, sx2 = 0.f, sk = 0.f, sk2 = 0.f;
#pragma unroll
    for (int i = 0; i < 2; ++i) {
        f32x4 xv = xr[tid + i * 256]; xs[i] = xv;
        f32x4 kv = kr[tid + i * 256]; ks[i] = kv;
#pragma unroll
        for (int c = 0; c < 4; ++c) {
            sx += xv[c]; sx2 += xv[c] * xv[c];
            sk += kv[c]; sk2 += kv[c] * kv[c];
        }
    }
#pragma unroll
    for (int o = 32; o; o >>= 1) {
        sx += __shfl_xor(sx, o); sx2 += __shfl_xor(sx2, o);
        sk += __shfl_xor(sk, o); sk2 += __shfl_xor(sk2, o);
    }
    __shared__ float red[16];
    const int wid = tid >> 6, lane = tid & 63;
    if (!lane) { red[wid] = sx; red[4 + wid] = sx2; red[8 + wid] = sk; red[12 + wid] = sk2; }
    __syncthreads();
    sx  = red[0] + red[1] + red[2] + red[3];
    sx2 = red[4] + red[5] + red[6] + red[7];
    sk  = red[8] + red[9] + red[10] + red[11];
    sk2 = red[12] + red[13] + red[14] + red[15];
    const float inv = 1.f / (float)HID;
    const float mx = sx * inv, vx = sx2 * inv - mx * mx;
    const float mk = sk * inv, vk = sk2 * inv - mk * mk;
    const float rx = rsqrtf(vx + 1e-5f), rk = rsqrtf(vk + 1e-5f);
    float dot = 0.f;
#pragma unroll
    for (int i = 0; i < 2; ++i) {
        const int v4 = tid + i * 256;
        f32x4 g4 = ((const f32x4*)gq)[v4];
        f32x4 b4 = ((const f32x4*)bq)[v4];
        f32x4 gk4 = ((const f32x4*)gk)[v4];
        f32x4 bk4 = ((const f32x4*)bk)[v4];
#pragma unroll
        for (int c = 0; c < 4; ++c) {
            float q  = (xs[i][c] - mx) * rx * g4[c] + b4[c];
            float kl = (ks[i][c] - mk) * rk * gk4[c] + bk4[c];
            dot += q * kl;
        }
    }
#pragma unroll
    for (int o = 32; o; o >>= 1) dot += __shfl_xor(dot, o);
    __syncthreads();
    if (!lane) red[wid] = dot;
    __syncthreads();
    if (tid == 0) {
        float gd = (red[0] + red[1] + red[2] + red[3]) * 0.022097086912079608f; // 1/sqrt(2048)
        float sg = (gd > 0.f) ? 1.f : ((gd < 0.f) ? -1.f : 0.f);
        float sv = sqrtf(fmaxf(fabsf(gd), 1e-6f)) * sg;
        gamma[m] = 1.f / (1.f + expf(-sv));
    }
}

// ================= 256x256 / BK=64, 2-barriers-per-K-tile bf16 MFMA GEMM =================
// C[m,n] = (rowscale[m]?) * sum_k A[m,k]*B[n,k]; A MxK (lda), B NxK (ldb), bf16.
// 512 thr = 8 waves (2M x 4N), per-wave out 128x64. LDS 128 KiB dynamic:
// A dbuf [0,64K), B dbuf [64K,128K). 256 rows x 128B per buffer, XOR-swizzle
// byte^=((row&7)<<4) on BOTH stage-source column and ds_read (involution).
// 2 barriers per K-tile (r5-validated); vmcnt(8) counted wait, never 0 in
// steady state. r7: (a) 2D XCD chunking — each XCD gets an 8x8 tile chunk
// (concurrent working set 64MB -> 16MB); (b) coalesced epilogue via LDS
// staging — fragment stores were 64B-scattered (measured 0.9 TB/s write on
// GEMM1); now each wave stores 1KB-contiguous rows. Grid MUST be 64x8 tiles.
template <bool SCALE, bool OUTBF16>
__global__ __launch_bounds__(512, 2)
void gemm8(const u16* __restrict__ A, int lda, const u16* __restrict__ Bm, int ldb,
           const float* __restrict__ rowscale, void* __restrict__ Cout,
           int M, int N, int K) {
    extern __shared__ char smem[];
    const int tid = threadIdx.x, wid = tid >> 6, lane = tid & 63;
    const int l15 = lane & 15, lhi = lane >> 4;
    const int wr = wid >> 2, wc = wid & 3;

    // 2D XCD chunking: xcd = id&7 owns an 8(m) x 8(n) tile chunk (tiles 64x8)
    const int id = blockIdx.x;
    const int xcd = id & 7, loc = id >> 3;
    const int mblk = ((xcd << 3) + (loc & 7)) << 8;
    const int nblk = (loc >> 3) << 8;

    f32x4 acc[8][4];
#pragma unroll
    for (int i = 0; i < 8; ++i)
#pragma unroll
        for (int j = 0; j < 4; ++j) acc[i][j] = f32x4{0.f, 0.f, 0.f, 0.f};

    // stage source: thread tid stages 16B to linear LDS o = h*16K + r*8K + tid*16
    // row = o>>7 (128 B/row), src col pre-swizzled so LDS[o] = global at swz(o)
    const int srow = tid >> 3;
    const int scol = ((tid & 7) << 3) ^ ((srow & 7) << 3);
    const u16* aS[4];
    const u16* bS[4];
#pragma unroll
    for (int h = 0; h < 2; ++h)
#pragma unroll
        for (int r = 0; r < 2; ++r) {
            aS[h * 2 + r] = A  + (size_t)(mblk + h * 128 + r * 64 + srow) * lda + scol;
            bS[h * 2 + r] = Bm + (size_t)(nblk + h * 128 + r * 64 + srow) * ldb + scol;
        }
    const int wb = wid * 1024;   // wave-uniform byte base

    const int koff0 = (lhi * 16) ^ ((l15 & 7) << 4);
    const int koff1 = (64 + lhi * 16) ^ ((l15 & 7) << 4);

    short8 ar[4][2], br[2][2][2];

#define STAGE_TILE(tt) do { const int q_ = (tt) & 1; const int kk_ = (tt) << 6;      \
        char* da_ = smem + q_ * 32768 + wb;                                          \
        char* db_ = smem + 65536 + q_ * 32768 + wb;                                  \
        gld_lds16(aS[0] + kk_, da_);         gld_lds16(aS[1] + kk_, da_ + 8192);     \
        gld_lds16(aS[2] + kk_, da_ + 16384); gld_lds16(aS[3] + kk_, da_ + 24576);    \
        gld_lds16(bS[0] + kk_, db_);         gld_lds16(bS[1] + kk_, db_ + 8192);     \
        gld_lds16(bS[2] + kk_, db_ + 16384); gld_lds16(bS[3] + kk_, db_ + 24576);    \
    } while (0)
#define LDA_SUB(mh, p) do {                                                          \
        const char* ab_ = smem + (p) * 32768 + (wr * 128 + (mh) * 64) * 128;         \
        _Pragma("unroll") for (int fm = 0; fm < 4; ++fm) {                           \
            const char* rb_ = ab_ + (fm * 16 + l15) * 128;                           \
            ar[fm][0] = *(const short8*)(rb_ + koff0);                               \
            ar[fm][1] = *(const short8*)(rb_ + koff1); } } while (0)
#define LDB_SUB(nh, p) do {                                                          \
        const char* bb_ = smem + 65536 + (p) * 32768 + (wc * 64 + (nh) * 32) * 128;  \
        _Pragma("unroll") for (int fn = 0; fn < 2; ++fn) {                           \
            const char* rb_ = bb_ + (fn * 16 + l15) * 128;                           \
            br[nh][fn][0] = *(const short8*)(rb_ + koff0);                           \
            br[nh][fn][1] = *(const short8*)(rb_ + koff1); } } while (0)
#define MMQ(mh, nh) do { __builtin_amdgcn_s_setprio(1);                              \
        _Pragma("unroll") for (int fm = 0; fm < 4; ++fm)                             \
        _Pragma("unroll") for (int fn = 0; fn < 2; ++fn) {                           \
            acc[(mh) * 4 + fm][(nh) * 2 + fn] = __builtin_amdgcn_mfma_f32_16x16x32_bf16( \
                ar[fm][0], br[nh][fn][0], acc[(mh) * 4 + fm][(nh) * 2 + fn], 0, 0, 0);   \
            acc[(mh) * 4 + fm][(nh) * 2 + fn] = __builtin_amdgcn_mfma_f32_16x16x32_bf16( \
                ar[fm][1], br[nh][fn][1], acc[(mh) * 4 + fm][(nh) * 2 + fn], 0, 0, 0); } \
        __builtin_amdgcn_s_setprio(0); } while (0)

    // prologue: tiles 0 and 1 fully staged (16 loads); wait oldest 8 (tile 0)
    STAGE_TILE(0);
    STAGE_TILE(1);
    asm volatile("s_waitcnt vmcnt(8)" ::: "memory");
    BAR();

    const int nk = K >> 6;
    for (int t = 0; t < nk; ++t) {
        const int p = t & 1;
        LDA_SUB(0, p); LDB_SUB(0, p);
        MMQ(0, 0);
        LDB_SUB(1, p);
        MMQ(0, 1);
        LDA_SUB(1, p);
        MMQ(1, 1);
        MMQ(1, 0);
        BAR();   // all waves done reading buffer p
        if (t + 2 < nk) {
            STAGE_TILE(t + 2);   // overwrite buffer p
            asm volatile("s_waitcnt vmcnt(8)" ::: "memory");   // drain own tile t+1
        } else {
            asm volatile("s_waitcnt vmcnt(0)" ::: "memory");   // tail drain
        }
        BAR();   // publish tile t+1
    }
#undef STAGE_TILE
#undef LDA_SUB
#undef LDB_SUB
#undef MMQ

    // ---- coalesced epilogue: acc -> LDS -> 1KB-contiguous global stores ----
    // fragment layout: D row=(lane>>4)*4+r, col=lane&15 (m89-verified)
    if (OUTBF16) {
        // single pass: 256 rows x 512B = 128KB
#pragma unroll
        for (int mi = 0; mi < 8; ++mi)
#pragma unroll
            for (int rr = 0; rr < 4; ++rr) {
                const int rl = wr * 128 + mi * 16 + lhi * 4 + rr;
                const float sc = SCALE ? rowscale[mblk + rl] : 1.0f;
#pragma unroll
                for (int nj = 0; nj < 4; ++nj) {
                    const int col = wc * 64 + nj * 16 + l15;
                    *(u16*)(smem + rl * 512 + col * 2) = f2bf(acc[mi][nj][rr] * sc);
                }
            }
        BAR();
#pragma unroll
        for (int rd = 0; rd < 16; ++rd) {
            const int byte = rd * 8192 + tid * 16;
            const int row = byte >> 9, cb = (byte & 511) >> 1;
            *(short8*)((u16*)Cout + (size_t)(mblk + row) * N + nblk + cb) =
                *(const short8*)(smem + byte);
        }
    } else {
        // two passes of 128 rows x 1024B = 128KB
#pragma unroll
        for (int pass = 0; pass < 2; ++pass) {
            if (wr == pass) {
#pragma unroll
                for (int mi = 0; mi < 8; ++mi)
#pragma unroll
                    for (int rr = 0; rr < 4; ++rr) {
                        const int rl = mi * 16 + lhi * 4 + rr;
                        const float sc = SCALE ? rowscale[mblk + pass * 128 + rl] : 1.0f;
#pragma unroll
                        for (int nj = 0; nj < 4; ++nj) {
                            const int col = wc * 64 + nj * 16 + l15;
                            *(float*)(smem + rl * 1024 + col * 4) = acc[mi][nj][rr] * sc;
                        }
                    }
            }
            BAR();
#pragma unroll
            for (int rd = 0; rd < 16; ++rd) {
                const int byte = rd * 8192 + tid * 16;
                const int row = byte >> 10, cb = (byte & 1023) >> 2;
                *(f32x4*)((float*)Cout + (size_t)(mblk + pass * 128 + row) * N + nblk + cb) =
                    *(const f32x4*)(smem + byte);
            }
            BAR();   // pass-1 LDS writes must wait for pass-0 reads
        }
    }
}

extern "C" void kernel_launch(void* const* d_in, const int* in_sizes, int n_in,
                              void* d_out, int out_size, void* d_ws, size_t ws_size,
                              hipStream_t stream) {
    const float* x      = (const float*)d_in[0];
    const int*   hashes = (const int*)d_in[1];
    const int*   offs   = (const int*)d_in[2];
    const float* emb    = (const float*)d_in[3];
    const float* conv_w = (const float*)d_in[4];
    const float* lncg   = (const float*)d_in[5];
    const float* lncb   = (const float*)d_in[6];
    const float* Wk     = (const float*)d_in[7];
    const float* Wv     = (const float*)d_in[8];
    const float* Wo     = (const float*)d_in[9];
    const float* lnkg   = (const float*)d_in[10];
    const float* lnkb   = (const float*)d_in[11];
    const float* lnqg   = (const float*)d_in[12];
    const float* lnqb   = (const float*)d_in[13];

    // ws layout: E (16.8MB) and value (67MB) alias the key region (134MB);
    // lifetimes: E ends at k_conv; key written by GEMM1, dead after k_gamma;
    // value written by GEMM2. Total ws = 172 MB.
    char* p = (char*)d_ws;
    float* key   = (float*)p;
    float* E     = (float*)p;
    u16*   value = (u16*)p;  p += (size_t)BT_ * HID * 4;
    u16*   A3    = (u16*)p;  p += (size_t)BT_ * K3 * 2;
    u16*   Wk3   = (u16*)p;  p += (size_t)HID * K3 * 2;
    u16*   Wvb   = (u16*)p;  p += (size_t)HID * ED * 2;
    u16*   Wob   = (u16*)p;  p += (size_t)HID * HID * 2;
    float* gamma = (float*)p; p += (size_t)BT_ * 4;

    hipFuncSetAttribute((const void*)gemm8<false, false>,
                        hipFuncAttributeMaxDynamicSharedMemorySize, 131072);
    hipFuncSetAttribute((const void*)gemm8<true, true>,
                        hipFuncAttributeMaxDynamicSharedMemorySize, 131072);

    k_cvt<<<(HID * ED + 255) / 256, 256, 0, stream>>>(Wv, Wvb, HID * ED);
    k_cvt<<<(HID * HID + 255) / 256, 256, 0, stream>>>(Wo, Wob, HID * HID);
    k_cvt_wk3<<<(HID * ED) / 256, 256, 0, stream>>>(Wk, Wk3);
    k_gather<<<BT_, 256, 0, stream>>>(hashes, offs, emb, E);
    k_conv<<<BT_, 256, 0, stream>>>(E, conv_w, lncg, lncb, A3);
    // key = [ehi|ehi|elo] @ [Wkhi|Wklo|Wkhi]^T  (K'=768) -> f32
    gemm8<false, false><<<dim3((BT_ / 256) * (HID / 256)), 512, 131072, stream>>>(
        A3, K3, Wk3, K3, nullptr, key, BT_, HID, K3);
    k_gamma<<<BT_, 256, 0, stream>>>(x, key, lnkg, lnkb, lnqg, lnqb, gamma);
    // value = gamma * (ehi @ Wv^T)  (K=256) -> bf16 (overwrites dead key)
    gemm8<true, true><<<dim3((BT_ / 256) * (HID / 256)), 512, 131072, stream>>>(
        A3, K3, Wvb, ED, gamma, value, BT_, HID, ED);
    // out = value @ Wo^T  (K=2048) -> f32
    gemm8<false, false><<<dim3((BT_ / 256) * (HID / 256)), 512, 131072, stream>>>(
        value, HID, Wob, HID, nullptr, d_out, BT_, HID, HID);
}

// Round 8
// 345.747 us; speedup vs baseline: 1.1162x; 1.0384x over previous
//
#include <hip/hip_runtime.h>
#include <stdint.h>
#include <math.h>

#define B_   4
#define T_   4096
#define BT_  16384
#define HID  2048
#define ED   256
#define HD   32
#define NH   8
#define K3   768   // packed K for split-precision key GEMM

typedef unsigned short u16;
typedef __attribute__((ext_vector_type(8))) short short8;
typedef __attribute__((ext_vector_type(4))) float f32x4;

typedef __attribute__((address_space(1))) void gvoid;
typedef __attribute__((address_space(3))) void lvoid;

__device__ __forceinline__ float bf2f(u16 h) {
    return __uint_as_float(((uint32_t)h) << 16);
}
__device__ __forceinline__ u16 f2bf(float f) {
    uint32_t u = __float_as_uint(f);
    u += 0x7FFFu + ((u >> 16) & 1u);   // round-to-nearest-even
    return (u16)(u >> 16);
}
__device__ __forceinline__ void gld_lds16(const void* g, void* l) {
    __builtin_amdgcn_global_load_lds((gvoid*)(uintptr_t)g, (lvoid*)(uintptr_t)l, 16, 0, 0);
}
__device__ __forceinline__ void BAR() {
    asm volatile("" ::: "memory");
    __builtin_amdgcn_s_barrier();
    asm volatile("" ::: "memory");
}

// ---------------- f32 -> bf16 convert ----------------
__global__ void k_cvt(const float* __restrict__ in, u16* __restrict__ out, int n) {
    int i = blockIdx.x * 256 + threadIdx.x;
    if (i < n) out[i] = f2bf(in[i]);
}

// ---- Wk -> packed [hi | lo | hi] rows of 768 (pairs with A3 = [hi | hi | lo]) ----
__global__ void k_cvt_wk3(const float* __restrict__ in, u16* __restrict__ out) {
    int i = blockIdx.x * 256 + threadIdx.x;   // over HID*ED
    int n = i >> 8, c = i & 255;
    float f = in[i];
    u16 h = f2bf(f);
    out[(size_t)n * K3 + c]       = h;
    out[(size_t)n * K3 + 256 + c] = f2bf(f - bf2f(h));
    out[(size_t)n * K3 + 512 + c] = h;
}

// ---------------- hash-embedding gather (f32) ----------------
__global__ void k_gather(const int* __restrict__ hashes, const int* __restrict__ offs,
                         const float* __restrict__ tab, float* __restrict__ E) {
    const int bt = blockIdx.x;
    const int tid = threadIdx.x;          // 256 = 8 heads x 32 dims
    const int head = tid >> 5, d = tid & 31;
    const int row = hashes[bt * NH + head] + offs[head];
    E[(size_t)bt * ED + tid] = tab[(size_t)row * HD + d];
}

// ---- conv + LN + silu + residual; writes A3 row = [e_hi | e_hi | e_lo] (768) ----
__global__ void k_conv(const float* __restrict__ E, const float* __restrict__ w,
                       const float* __restrict__ lng, const float* __restrict__ lnb,
                       u16* __restrict__ a3) {
    const int bt = blockIdx.x;
    const int b = bt >> 12;               // T_ = 4096
    const int t = bt & 4095;
    const int ch = threadIdx.x;           // 256
    float c = 0.f;
#pragma unroll
    for (int k = 0; k < 4; ++k) {
        int tt = t - 9 + 3 * k;           // taps at t-9, t-6, t-3, t
        if (tt >= 0)
            c += w[ch * 4 + k] * E[((size_t)(b * T_ + tt)) * ED + ch];
    }
    float s = c, s2 = c * c;
#pragma unroll
    for (int o = 32; o; o >>= 1) { s += __shfl_xor(s, o); s2 += __shfl_xor(s2, o); }
    __shared__ float red[8];
    const int wid = ch >> 6, lane = ch & 63;
    if (!lane) { red[wid] = s; red[4 + wid] = s2; }
    __syncthreads();
    s  = red[0] + red[1] + red[2] + red[3];
    s2 = red[4] + red[5] + red[6] + red[7];
    const float mean = s * (1.f / 256.f);
    const float var  = s2 * (1.f / 256.f) - mean * mean;
    float ln = (c - mean) * rsqrtf(var + 1e-5f) * lng[ch] + lnb[ch];
    float si = ln / (1.f + expf(-ln));    // silu
    float ev = E[(size_t)bt * ED + ch] + si;
    u16 h = f2bf(ev);
    a3[(size_t)bt * K3 + ch]       = h;
    a3[(size_t)bt * K3 + 256 + ch] = h;
    a3[(size_t)bt * K3 + 512 + ch] = f2bf(ev - bf2f(h));
}

// ---------------- per-row x stats: mu, rsqrt(var+eps) ----------------
__global__ void k_xstat(const float* __restrict__ x, float* __restrict__ xs) {
    const int m = blockIdx.x;
    const int tid = threadIdx.x;          // 256 thr, 2 float4 each
    const f32x4* xr = (const f32x4*)(x + (size_t)m * HID);
    float sx = 0.f, sx2 = 0.f;
#pragma unroll
    for (int i = 0; i < 2; ++i) {
        f32x4 xv = xr[tid + i * 256];
#pragma unroll
        for (int c = 0; c < 4; ++c) { sx += xv[c]; sx2 += xv[c] * xv[c]; }
    }
#pragma unroll
    for (int o = 32; o; o >>= 1) { sx += __shfl_xor(sx, o); sx2 += __shfl_xor(sx2, o); }
    __shared__ float red[8];
    const int wid = tid >> 6, lane = tid & 63;
    if (!lane) { red[wid] = sx; red[4 + wid] = sx2; }
    __syncthreads();
    if (tid == 0) {
        sx  = red[0] + red[1] + red[2] + red[3];
        sx2 = red[4] + red[5] + red[6] + red[7];
        const float inv = 1.f / (float)HID;
        const float mu = sx * inv, var = sx2 * inv - mu * mu;
        xs[m * 2]     = mu;
        xs[m * 2 + 1] = rsqrtf(var + 1e-5f);
    }
}

// ---------------- finalize gamma from 8 partial slices ----------------
// dot = rk*(T1 - mu_k*T2) + T3 ; partial[m][nb][5] = {S1,S2,T1,T2,T3}
__global__ void k_gamma2(const float* __restrict__ partial, float* __restrict__ gamma) {
    const int m = blockIdx.x * 256 + threadIdx.x;
    float s[5] = {0.f, 0.f, 0.f, 0.f, 0.f};
    const float* p = partial + (size_t)m * 40;
#pragma unroll
    for (int nb = 0; nb < 8; ++nb)
#pragma unroll
        for (int v = 0; v < 5; ++v) s[v] += p[nb * 5 + v];
    const float inv = 1.f / (float)HID;
    const float mu = s[0] * inv, var = s[1] * inv - mu * mu;
    const float rk = rsqrtf(var + 1e-5f);
    const float dot = rk * (s[2] - mu * s[3]) + s[4];
    const float gd = dot * 0.022097086912079608f;   // 1/sqrt(2048)
    const float sg = (gd > 0.f) ? 1.f : ((gd < 0.f) ? -1.f : 0.f);
    const float sv = sqrtf(fmaxf(fabsf(gd), 1e-6f)) * sg;
    gamma[m] = 1.f / (1.f + expf(-sv));
}

// ================= 256x256 / BK=64, 2-barriers-per-K-tile bf16 MFMA GEMM =================
// C[m,n] = sum_k A[m,k]*B[n,k]; A MxK (lda), B NxK (ldb), bf16.
// 512 thr = 8 waves (2M x 4N), per-wave out 128x64. LDS 128 KiB dynamic:
// A dbuf [0,64K), B dbuf [64K,128K). 256 rows x 128B per buffer, XOR-swizzle
// byte^=((row&7)<<4) on BOTH stage-source column and ds_read (involution).
// 2 barriers per K-tile (r5); vmcnt(8) counted wait, never 0 in steady state.
// 2D XCD chunking: xcd = id&7 owns an 8(m) x 8(n) tile chunk (r7: FETCH 270->98MB).
// EPI: 0 = f32 store; 1 = bf16 store with rowscale; 2 = key-reduction epilogue
// (fused gamma path: per-row partials {S1,S2,T1,T2,T3} over this block's 256
// cols from acc IN REGISTERS — key is never materialized; saves 268 MB HBM).
template <int EPI>
__global__ __launch_bounds__(512, 2)
void gemm8(const u16* __restrict__ A, int lda, const u16* __restrict__ Bm, int ldb,
           const float* __restrict__ rowscale, void* __restrict__ Cout,
           int M, int N, int K,
           const float* __restrict__ xq, const float* __restrict__ xs,
           const float* __restrict__ gq, const float* __restrict__ bq,
           const float* __restrict__ gk, const float* __restrict__ bk,
           float* __restrict__ partial) {
    extern __shared__ char smem[];
    const int tid = threadIdx.x, wid = tid >> 6, lane = tid & 63;
    const int l15 = lane & 15, lhi = lane >> 4;
    const int wr = wid >> 2, wc = wid & 3;

    const int id = blockIdx.x;
    const int xcd = id & 7, loc = id >> 3;
    const int mblk = ((xcd << 3) + (loc & 7)) << 8;
    const int nblk = (loc >> 3) << 8;

    f32x4 acc[8][4];
#pragma unroll
    for (int i = 0; i < 8; ++i)
#pragma unroll
        for (int j = 0; j < 4; ++j) acc[i][j] = f32x4{0.f, 0.f, 0.f, 0.f};

    const int srow = tid >> 3;
    const int scol = ((tid & 7) << 3) ^ ((srow & 7) << 3);
    const u16* aS[4];
    const u16* bS[4];
#pragma unroll
    for (int h = 0; h < 2; ++h)
#pragma unroll
        for (int r = 0; r < 2; ++r) {
            aS[h * 2 + r] = A  + (size_t)(mblk + h * 128 + r * 64 + srow) * lda + scol;
            bS[h * 2 + r] = Bm + (size_t)(nblk + h * 128 + r * 64 + srow) * ldb + scol;
        }
    const int wb = wid * 1024;

    const int koff0 = (lhi * 16) ^ ((l15 & 7) << 4);
    const int koff1 = (64 + lhi * 16) ^ ((l15 & 7) << 4);

    short8 ar[4][2], br[2][2][2];

#define STAGE_TILE(tt) do { const int q_ = (tt) & 1; const int kk_ = (tt) << 6;      \
        char* da_ = smem + q_ * 32768 + wb;                                          \
        char* db_ = smem + 65536 + q_ * 32768 + wb;                                  \
        gld_lds16(aS[0] + kk_, da_);         gld_lds16(aS[1] + kk_, da_ + 8192);     \
        gld_lds16(aS[2] + kk_, da_ + 16384); gld_lds16(aS[3] + kk_, da_ + 24576);    \
        gld_lds16(bS[0] + kk_, db_);         gld_lds16(bS[1] + kk_, db_ + 8192);     \
        gld_lds16(bS[2] + kk_, db_ + 16384); gld_lds16(bS[3] + kk_, db_ + 24576);    \
    } while (0)
#define LDA_SUB(mh, p) do {                                                          \
        const char* ab_ = smem + (p) * 32768 + (wr * 128 + (mh) * 64) * 128;         \
        _Pragma("unroll") for (int fm = 0; fm < 4; ++fm) {                           \
            const char* rb_ = ab_ + (fm * 16 + l15) * 128;                           \
            ar[fm][0] = *(const short8*)(rb_ + koff0);                               \
            ar[fm][1] = *(const short8*)(rb_ + koff1); } } while (0)
#define LDB_SUB(nh, p) do {                                                          \
        const char* bb_ = smem + 65536 + (p) * 32768 + (wc * 64 + (nh) * 32) * 128;  \
        _Pragma("unroll") for (int fn = 0; fn < 2; ++fn) {                           \
            const char* rb_ = bb_ + (fn * 16 + l15) * 128;                           \
            br[nh][fn][0] = *(const short8*)(rb_ + koff0);                           \
            br[nh][fn][1] = *(const short8*)(rb_ + koff1); } } while (0)
#define MMQ(mh, nh) do { __builtin_amdgcn_s_setprio(1);                              \
        _Pragma("unroll") for (int fm = 0; fm < 4; ++fm)                             \
        _Pragma("unroll") for (int fn = 0; fn < 2; ++fn) {                           \
            acc[(mh) * 4 + fm][(nh) * 2 + fn] = __builtin_amdgcn_mfma_f32_16x16x32_bf16( \
                ar[fm][0], br[nh][fn][0], acc[(mh) * 4 + fm][(nh) * 2 + fn], 0, 0, 0);   \
            acc[(mh) * 4 + fm][(nh) * 2 + fn] = __builtin_amdgcn_mfma_f32_16x16x32_bf16( \
                ar[fm][1], br[nh][fn][1], acc[(mh) * 4 + fm][(nh) * 2 + fn], 0, 0, 0); } \
        __builtin_amdgcn_s_setprio(0); } while (0)

    STAGE_TILE(0);
    STAGE_TILE(1);
    asm volatile("s_waitcnt vmcnt(8)" ::: "memory");
    BAR();

    const int nk = K >> 6;
    for (int t = 0; t < nk; ++t) {
        const int p = t & 1;
        LDA_SUB(0, p); LDB_SUB(0, p);
        MMQ(0, 0);
        LDB_SUB(1, p);
        MMQ(0, 1);
        LDA_SUB(1, p);
        MMQ(1, 1);
        MMQ(1, 0);
        BAR();
        if (t + 2 < nk) {
            STAGE_TILE(t + 2);
            asm volatile("s_waitcnt vmcnt(8)" ::: "memory");
        } else {
            asm volatile("s_waitcnt vmcnt(0)" ::: "memory");
        }
        BAR();
    }
#undef STAGE_TILE
#undef LDA_SUB
#undef LDB_SUB
#undef MMQ

    if (EPI == 2) {
        // ---- fused key->gamma partial reduction (key stays in registers) ----
        // per-lane col params for its 4 nj columns
        float gqv[4], bqv[4], gkv[4], bkv[4];
#pragma unroll
        for (int nj = 0; nj < 4; ++nj) {
            const int n = nblk + wc * 64 + nj * 16 + l15;
            gqv[nj] = gq[n]; bqv[nj] = bq[n]; gkv[nj] = gk[n]; bkv[nj] = bk[n];
        }
        float* red = (float*)smem;           // [256 rows][4 wc][5] = 20 KB
#pragma unroll
        for (int mi = 0; mi < 8; ++mi) {
#pragma unroll
            for (int rr = 0; rr < 4; ++rr) {
                const int rloc = wr * 128 + mi * 16 + lhi * 4 + rr;
                const int m = mblk + rloc;
                const float mu = xs[m * 2], rx = xs[m * 2 + 1];
                float s1 = 0.f, s2 = 0.f, t1 = 0.f, t2 = 0.f, t3 = 0.f;
#pragma unroll
                for (int nj = 0; nj < 4; ++nj) {
                    const float kv = acc[mi][nj][rr];
                    const float xv = xq[(size_t)m * N + nblk + wc * 64 + nj * 16 + l15];
                    const float q  = (xv - mu) * rx * gqv[nj] + bqv[nj];
                    const float qg = q * gkv[nj];
                    s1 += kv; s2 += kv * kv;
                    t1 += qg * kv; t2 += qg; t3 += q * bkv[nj];
                }
#pragma unroll
                for (int o = 1; o < 16; o <<= 1) {
                    s1 += __shfl_xor(s1, o); s2 += __shfl_xor(s2, o);
                    t1 += __shfl_xor(t1, o); t2 += __shfl_xor(t2, o);
                    t3 += __shfl_xor(t3, o);
                }
                if (l15 == 0) {
                    float* d = red + ((size_t)rloc * 4 + wc) * 5;
                    d[0] = s1; d[1] = s2; d[2] = t1; d[3] = t2; d[4] = t3;
                }
            }
        }
        BAR();
        const int nb = nblk >> 8;
        for (int e = tid; e < 1280; e += 512) {
            const int row = e / 5, v = e - row * 5;
            const float s = red[((size_t)row * 4 + 0) * 5 + v] + red[((size_t)row * 4 + 1) * 5 + v]
                          + red[((size_t)row * 4 + 2) * 5 + v] + red[((size_t)row * 4 + 3) * 5 + v];
            partial[((size_t)(mblk + row) * 8 + nb) * 5 + v] = s;
        }
    } else {
        // direct fragment epilogue (r5): D row=(lane>>4)*4+r, col=lane&15
#pragma unroll
        for (int mi = 0; mi < 8; ++mi) {
#pragma unroll
            for (int rr = 0; rr < 4; ++rr) {
                const int m = mblk + wr * 128 + mi * 16 + lhi * 4 + rr;
                const float sc = (EPI == 1) ? rowscale[m] : 1.0f;
#pragma unroll
                for (int nj = 0; nj < 4; ++nj) {
                    const int n = nblk + wc * 64 + nj * 16 + l15;
                    const float v = acc[mi][nj][rr] * sc;
                    if (EPI == 1) ((u16*)Cout)[(size_t)m * N + n] = f2bf(v);
                    else          ((float*)Cout)[(size_t)m * N + n] = v;
                }
            }
        }
    }
}

extern "C" void kernel_launch(void* const* d_in, const int* in_sizes, int n_in,
                              void* d_out, int out_size, void* d_ws, size_t ws_size,
                              hipStream_t stream) {
    const float* x      = (const float*)d_in[0];
    const int*   hashes = (const int*)d_in[1];
    const int*   offs   = (const int*)d_in[2];
    const float* emb    = (const float*)d_in[3];
    const float* conv_w = (const float*)d_in[4];
    const float* lncg   = (const float*)d_in[5];
    const float* lncb   = (const float*)d_in[6];
    const float* Wk     = (const float*)d_in[7];
    const float* Wv     = (const float*)d_in[8];
    const float* Wo     = (const float*)d_in[9];
    const float* lnkg   = (const float*)d_in[10];
    const float* lnkb   = (const float*)d_in[11];
    const float* lnqg   = (const float*)d_in[12];
    const float* lnqb   = (const float*)d_in[13];

    // ws layout (~107 MB): E (16.8, dead after k_conv) aliases value (67, written
    // by GEMM2 later). key is never materialized (fused gamma path).
    char* p = (char*)d_ws;
    float* E     = (float*)p;
    u16*   value = (u16*)p;   p += (size_t)BT_ * HID * 2;   // 67 MB (E fits inside)
    u16*   A3    = (u16*)p;   p += (size_t)BT_ * K3 * 2;    // 25 MB
    u16*   Wk3   = (u16*)p;   p += (size_t)HID * K3 * 2;    // 3 MB
    u16*   Wvb   = (u16*)p;   p += (size_t)HID * ED * 2;    // 1 MB
    u16*   Wob   = (u16*)p;   p += (size_t)HID * HID * 2;   // 8.4 MB
    float* xs    = (float*)p; p += (size_t)BT_ * 2 * 4;     // 128 KB
    float* part  = (float*)p; p += (size_t)BT_ * 8 * 5 * 4; // 2.6 MB
    float* gamma = (float*)p; p += (size_t)BT_ * 4;         // 64 KB

    hipFuncSetAttribute((const void*)gemm8<0>,
                        hipFuncAttributeMaxDynamicSharedMemorySize, 131072);
    hipFuncSetAttribute((const void*)gemm8<1>,
                        hipFuncAttributeMaxDynamicSharedMemorySize, 131072);
    hipFuncSetAttribute((const void*)gemm8<2>,
                        hipFuncAttributeMaxDynamicSharedMemorySize, 131072);

    k_cvt<<<(HID * ED + 255) / 256, 256, 0, stream>>>(Wv, Wvb, HID * ED);
    k_cvt<<<(HID * HID + 255) / 256, 256, 0, stream>>>(Wo, Wob, HID * HID);
    k_cvt_wk3<<<(HID * ED) / 256, 256, 0, stream>>>(Wk, Wk3);
    k_gather<<<BT_, 256, 0, stream>>>(hashes, offs, emb, E);
    k_conv<<<BT_, 256, 0, stream>>>(E, conv_w, lncg, lncb, A3);
    k_xstat<<<BT_, 256, 0, stream>>>(x, xs);

    const dim3 grid((BT_ / 256) * (HID / 256));   // 512 = 64x8 tiles
    // key partials: [ehi|ehi|elo] @ [Wkhi|Wklo|Wkhi]^T (K'=768), reduce in epilogue
    gemm8<2><<<grid, 512, 131072, stream>>>(
        A3, K3, Wk3, K3, nullptr, nullptr, BT_, HID, K3,
        x, xs, lnqg, lnqb, lnkg, lnkb, part);
    k_gamma2<<<BT_ / 256, 256, 0, stream>>>(part, gamma);
    // value = gamma * (ehi @ Wv^T)  (K=256) -> bf16
    gemm8<1><<<grid, 512, 131072, stream>>>(
        A3, K3, Wvb, ED, gamma, value, BT_, HID, ED,
        nullptr, nullptr, nullptr, nullptr, nullptr, nullptr, nullptr);
    // out = value @ Wo^T  (K=2048) -> f32
    gemm8<0><<<grid, 512, 131072, stream>>>(
        value, HID, Wob, HID, nullptr, d_out, BT_, HID, HID,
        nullptr, nullptr, nullptr, nullptr, nullptr, nullptr, nullptr);
}

// Round 10
// 338.637 us; speedup vs baseline: 1.1397x; 1.0210x over previous
//
#include <hip/hip_runtime.h>
#include <stdint.h>
#include <math.h>

#define B_   4
#define T_   4096
#define BT_  16384
#define HID  2048
#define ED   256
#define HD   32
#define NH   8
#define K3   768   // packed K for split-precision key GEMM

typedef unsigned short u16;
typedef __attribute__((ext_vector_type(8))) short short8;
typedef __attribute__((ext_vector_type(4))) float f32x4;

typedef __attribute__((address_space(1))) void gvoid;
typedef __attribute__((address_space(3))) void lvoid;

__device__ __forceinline__ float bf2f(u16 h) {
    return __uint_as_float(((uint32_t)h) << 16);
}
__device__ __forceinline__ u16 f2bf(float f) {
    uint32_t u = __float_as_uint(f);
    u += 0x7FFFu + ((u >> 16) & 1u);   // round-to-nearest-even
    return (u16)(u >> 16);
}
__device__ __forceinline__ void gld_lds16(const void* g, void* l) {
    __builtin_amdgcn_global_load_lds((gvoid*)(uintptr_t)g, (lvoid*)(uintptr_t)l, 16, 0, 0);
}
__device__ __forceinline__ void BAR() {
    asm volatile("" ::: "memory");
    __builtin_amdgcn_s_barrier();
    asm volatile("" ::: "memory");
}

// ---------------- f32 -> bf16 convert ----------------
__global__ void k_cvt(const float* __restrict__ in, u16* __restrict__ out, int n) {
    int i = blockIdx.x * 256 + threadIdx.x;
    if (i < n) out[i] = f2bf(in[i]);
}

// ---- Wk -> packed [hi | lo | hi] rows of 768 (pairs with A3 = [hi | hi | lo]) ----
__global__ void k_cvt_wk3(const float* __restrict__ in, u16* __restrict__ out) {
    int i = blockIdx.x * 256 + threadIdx.x;   // over HID*ED
    int n = i >> 8, c = i & 255;
    float f = in[i];
    u16 h = f2bf(f);
    out[(size_t)n * K3 + c]       = h;
    out[(size_t)n * K3 + 256 + c] = f2bf(f - bf2f(h));
    out[(size_t)n * K3 + 512 + c] = h;
}

// ---------------- hash-embedding gather (f32) ----------------
__global__ void k_gather(const int* __restrict__ hashes, const int* __restrict__ offs,
                         const float* __restrict__ tab, float* __restrict__ E) {
    const int bt = blockIdx.x;
    const int tid = threadIdx.x;          // 256 = 8 heads x 32 dims
    const int head = tid >> 5, d = tid & 31;
    const int row = hashes[bt * NH + head] + offs[head];
    E[(size_t)bt * ED + tid] = tab[(size_t)row * HD + d];
}

// ---- conv + LN + silu + residual; writes A3 row = [e_hi | e_hi | e_lo] (768) ----
__global__ void k_conv(const float* __restrict__ E, const float* __restrict__ w,
                       const float* __restrict__ lng, const float* __restrict__ lnb,
                       u16* __restrict__ a3) {
    const int bt = blockIdx.x;
    const int b = bt >> 12;               // T_ = 4096
    const int t = bt & 4095;
    const int ch = threadIdx.x;           // 256
    float c = 0.f;
#pragma unroll
    for (int k = 0; k < 4; ++k) {
        int tt = t - 9 + 3 * k;           // taps at t-9, t-6, t-3, t
        if (tt >= 0)
            c += w[ch * 4 + k] * E[((size_t)(b * T_ + tt)) * ED + ch];
    }
    float s = c, s2 = c * c;
#pragma unroll
    for (int o = 32; o; o >>= 1) { s += __shfl_xor(s, o); s2 += __shfl_xor(s2, o); }
    __shared__ float red[8];
    const int wid = ch >> 6, lane = ch & 63;
    if (!lane) { red[wid] = s; red[4 + wid] = s2; }
    __syncthreads();
    s  = red[0] + red[1] + red[2] + red[3];
    s2 = red[4] + red[5] + red[6] + red[7];
    const float mean = s * (1.f / 256.f);
    const float var  = s2 * (1.f / 256.f) - mean * mean;
    float ln = (c - mean) * rsqrtf(var + 1e-5f) * lng[ch] + lnb[ch];
    float si = ln / (1.f + expf(-ln));    // silu
    float ev = E[(size_t)bt * ED + ch] + si;
    u16 h = f2bf(ev);
    a3[(size_t)bt * K3 + ch]       = h;
    a3[(size_t)bt * K3 + 256 + ch] = h;
    a3[(size_t)bt * K3 + 512 + ch] = f2bf(ev - bf2f(h));
}

// ---------------- per-row x stats: mu, rsqrt(var+eps) ----------------
__global__ void k_xstat(const float* __restrict__ x, float* __restrict__ xs) {
    const int m = blockIdx.x;
    const int tid = threadIdx.x;          // 256 thr, 2 float4 each
    const f32x4* xr = (const f32x4*)(x + (size_t)m * HID);
    float sx = 0.f, sx2 = 0.f;
#pragma unroll
    for (int i = 0; i < 2; ++i) {
        f32x4 xv = xr[tid + i * 256];
#pragma unroll
        for (int c = 0; c < 4; ++c) { sx += xv[c]; sx2 += xv[c] * xv[c]; }
    }
#pragma unroll
    for (int o = 32; o; o >>= 1) { sx += __shfl_xor(sx, o); sx2 += __shfl_xor(sx2, o); }
    __shared__ float red[8];
    const int wid = tid >> 6, lane = tid & 63;
    if (!lane) { red[wid] = sx; red[4 + wid] = sx2; }
    __syncthreads();
    if (tid == 0) {
        sx  = red[0] + red[1] + red[2] + red[3];
        sx2 = red[4] + red[5] + red[6] + red[7];
        const float inv = 1.f / (float)HID;
        const float mu = sx * inv, var = sx2 * inv - mu * mu;
        xs[m * 2]     = mu;
        xs[m * 2 + 1] = rsqrtf(var + 1e-5f);
    }
}

// ---------------- finalize gamma from 8 partial slices ----------------
// dot = rk*(T1 - mu_k*T2) + T3 ; partial[m][nb][5] = {S1,S2,T1,T2,T3}
__global__ void k_gamma2(const float* __restrict__ partial, float* __restrict__ gamma) {
    const int m = blockIdx.x * 256 + threadIdx.x;
    float s[5] = {0.f, 0.f, 0.f, 0.f, 0.f};
    const float* p = partial + (size_t)m * 40;
#pragma unroll
    for (int nb = 0; nb < 8; ++nb)
#pragma unroll
        for (int v = 0; v < 5; ++v) s[v] += p[nb * 5 + v];
    const float inv = 1.f / (float)HID;
    const float mu = s[0] * inv, var = s[1] * inv - mu * mu;
    const float rk = rsqrtf(var + 1e-5f);
    const float dot = rk * (s[2] - mu * s[3]) + s[4];
    const float gd = dot * 0.022097086912079608f;   // 1/sqrt(2048)
    const float sg = (gd > 0.f) ? 1.f : ((gd < 0.f) ? -1.f : 0.f);
    const float sv = sqrtf(fmaxf(fabsf(gd), 1e-6f)) * sg;
    gamma[m] = 1.f / (1.f + expf(-sv));
}

// ================= 256x256 / BK=64 bf16 MFMA GEMM — pipelined, chunk-aligned =================
// C[m,n] = sum_k A[m,k]*B[n,k]; A MxK (lda), B NxK (ldb), bf16.
// 512 thr = 8 waves; per-wave out 128x64. LDS 128 KiB: A dbuf [0,64K), B dbuf
// [64K,128K); 256 rows x 128B per buf; XOR-swizzle byte^=((row&7)<<4) on
// stage-source col and ds_read (involution).
// r10 FIX of r9's race: reads are now CHUNK-PURE —
//   A row = mh*128 + wr*64 + fm*16 + l15  (P1 reads exactly A h0, P3 exactly h1)
//   B row = nh*128 + wc*32 + fn*16 + l15  (P1 reads exactly B h0, P2 exactly h1)
// (r9 had wr*128+mh*64: each read phase spanned both stage-halves, so the P2
// restage of h0 clobbered rows wr=0 still needed at P3.)
// Schedule (tile t, buf p=t&1): P1 reads Ah0,Bh0 + stage Ah1(t+1)->p^1 (freed
// (t-1).P3); P2 reads Bh1 + stage Ah0(t+2)->p (freed P1); P3 reads Ah1 + stage
// Bh0(t+2)->p (freed P1); P4 regs-only + stage Bh1(t+2)->p (freed P2), then
// single counted vmcnt(6): leaves the 3 halves staged this tile, drains ALL of
// tile t+1 (each drained load issued 4-8 phases ~600-1200cyc ago). Tail vmcnt(0).
// EPI: 0 = f32 store; 1 = bf16 store with rowscale; 2 = fused key->gamma
// partial reduction (key never materialized; saves 268 MB HBM).
template <int EPI>
__global__ __launch_bounds__(512, 2)
void gemm8(const u16* __restrict__ A, int lda, const u16* __restrict__ Bm, int ldb,
           const float* __restrict__ rowscale, void* __restrict__ Cout,
           int M, int N, int K,
           const float* __restrict__ xq, const float* __restrict__ xs,
           const float* __restrict__ gq, const float* __restrict__ bq,
           const float* __restrict__ gk, const float* __restrict__ bk,
           float* __restrict__ partial) {
    extern __shared__ char smem[];
    const int tid = threadIdx.x, wid = tid >> 6, lane = tid & 63;
    const int l15 = lane & 15, lhi = lane >> 4;
    const int wr = wid >> 2, wc = wid & 3;

    // 2D XCD chunking: xcd = id&7 owns an 8(m) x 8(n) tile chunk (r7: FETCH 270->98MB)
    const int id = blockIdx.x;
    const int xcd = id & 7, loc = id >> 3;
    const int mblk = ((xcd << 3) + (loc & 7)) << 8;
    const int nblk = (loc >> 3) << 8;

    f32x4 acc[8][4];
#pragma unroll
    for (int i = 0; i < 8; ++i)
#pragma unroll
        for (int j = 0; j < 4; ++j) acc[i][j] = f32x4{0.f, 0.f, 0.f, 0.f};

    const int srow = tid >> 3;
    const int scol = ((tid & 7) << 3) ^ ((srow & 7) << 3);
    const u16* aS[4];
    const u16* bS[4];
#pragma unroll
    for (int h = 0; h < 2; ++h)
#pragma unroll
        for (int r = 0; r < 2; ++r) {
            aS[h * 2 + r] = A  + (size_t)(mblk + h * 128 + r * 64 + srow) * lda + scol;
            bS[h * 2 + r] = Bm + (size_t)(nblk + h * 128 + r * 64 + srow) * ldb + scol;
        }
    const int wb = wid * 1024;

    const int koff0 = (lhi * 16) ^ ((l15 & 7) << 4);
    const int koff1 = (64 + lhi * 16) ^ ((l15 & 7) << 4);

    short8 ar[4][2], br[2][2][2];

// stage ONE half-tile (2 gld_lds/thread = 16KB): A-half h (rows h*128..+127)
#define SA(h, tt) do { const int kk_ = (tt) << 6;                                    \
        char* d_ = smem + (((tt) & 1) * 32768) + (h) * 16384 + wb;                   \
        gld_lds16(aS[(h) * 2 + 0] + kk_, d_);                                        \
        gld_lds16(aS[(h) * 2 + 1] + kk_, d_ + 8192); } while (0)
#define SB(h, tt) do { const int kk_ = (tt) << 6;                                    \
        char* d_ = smem + 65536 + (((tt) & 1) * 32768) + (h) * 16384 + wb;           \
        gld_lds16(bS[(h) * 2 + 0] + kk_, d_);                                        \
        gld_lds16(bS[(h) * 2 + 1] + kk_, d_ + 8192); } while (0)
// chunk-pure reads: A rows mh*128 + wr*64 + fm*16 + l15
#define LDA_SUB(mh, p) do {                                                          \
        const char* ab_ = smem + (p) * 32768 + ((mh) * 128 + wr * 64) * 128;         \
        _Pragma("unroll") for (int fm = 0; fm < 4; ++fm) {                           \
            const char* rb_ = ab_ + (fm * 16 + l15) * 128;                           \
            ar[fm][0] = *(const short8*)(rb_ + koff0);                               \
            ar[fm][1] = *(const short8*)(rb_ + koff1); } } while (0)
// B rows nh*128 + wc*32 + fn*16 + l15
#define LDB_SUB(nh, p) do {                                                          \
        const char* bb_ = smem + 65536 + (p) * 32768 + ((nh) * 128 + wc * 32) * 128; \
        _Pragma("unroll") for (int fn = 0; fn < 2; ++fn) {                           \
            const char* rb_ = bb_ + (fn * 16 + l15) * 128;                           \
            br[nh][fn][0] = *(const short8*)(rb_ + koff0);                           \
            br[nh][fn][1] = *(const short8*)(rb_ + koff1); } } while (0)
#define MMQ(mh, nh) do { __builtin_amdgcn_s_setprio(1);                              \
        _Pragma("unroll") for (int fm = 0; fm < 4; ++fm)                             \
        _Pragma("unroll") for (int fn = 0; fn < 2; ++fn) {                           \
            acc[(mh) * 4 + fm][(nh) * 2 + fn] = __builtin_amdgcn_mfma_f32_16x16x32_bf16( \
                ar[fm][0], br[nh][fn][0], acc[(mh) * 4 + fm][(nh) * 2 + fn], 0, 0, 0);   \
            acc[(mh) * 4 + fm][(nh) * 2 + fn] = __builtin_amdgcn_mfma_f32_16x16x32_bf16( \
                ar[fm][1], br[nh][fn][1], acc[(mh) * 4 + fm][(nh) * 2 + fn], 0, 0, 0); } \
        __builtin_amdgcn_s_setprio(0); } while (0)

    // prologue: tiles 0,1 fully staged (16 loads); drain tile 0 (oldest 8)
    SA(0, 0); SA(1, 0); SB(0, 0); SB(1, 0);
    SA(0, 1); SA(1, 1); SB(0, 1); SB(1, 1);
    asm volatile("s_waitcnt vmcnt(8)" ::: "memory");
    BAR();

    const int nk = K >> 6;
    for (int t = 0; t < nk; ++t) {
        const int p = t & 1;
        // P1: reads Ah0,Bh0 of buf p; stage Ah1(t+1) -> p^1 (freed (t-1).P3)
        LDA_SUB(0, p); LDB_SUB(0, p);
        if (t >= 1 && t + 1 < nk) SA(1, t + 1);
        BAR(); MMQ(0, 0); BAR();
        // P2: reads Bh1; stage Ah0(t+2) -> p (region freed at P1)
        LDB_SUB(1, p);
        if (t + 2 < nk) SA(0, t + 2);
        BAR(); MMQ(0, 1); BAR();
        // P3: reads Ah1; stage Bh0(t+2) -> p (freed at P1)
        LDA_SUB(1, p);
        if (t + 2 < nk) SB(0, t + 2);
        BAR(); MMQ(1, 0); BAR();
        // P4: regs only; stage Bh1(t+2) -> p (freed at P2); vmcnt(6) leaves the
        // 3 halves staged this tile, drains all of t+1 (incl. Ah1(t+1) from P1)
        if (t + 2 < nk) {
            SB(1, t + 2);
            asm volatile("s_waitcnt vmcnt(6)" ::: "memory");
        } else {
            asm volatile("s_waitcnt vmcnt(0)" ::: "memory");
        }
        BAR(); MMQ(1, 1); BAR();
    }
#undef SA
#undef SB
#undef LDA_SUB
#undef LDB_SUB
#undef MMQ

    if (EPI == 2) {
        // ---- fused key->gamma partial reduction (key stays in registers) ----
        float gqv[4], bqv[4], gkv[4], bkv[4];
#pragma unroll
        for (int nj = 0; nj < 4; ++nj) {
            const int n = nblk + (nj >> 1) * 128 + wc * 32 + (nj & 1) * 16 + l15;
            gqv[nj] = gq[n]; bqv[nj] = bq[n]; gkv[nj] = gk[n]; bkv[nj] = bk[n];
        }
        float* red = (float*)smem;           // [256 rows][4 wc][5] = 20 KB
#pragma unroll
        for (int mi = 0; mi < 8; ++mi) {
#pragma unroll
            for (int rr = 0; rr < 4; ++rr) {
                const int rloc = (mi >> 2) * 128 + wr * 64 + (mi & 3) * 16 + lhi * 4 + rr;
                const int m = mblk + rloc;
                const float mu = xs[m * 2], rx = xs[m * 2 + 1];
                float s1 = 0.f, s2 = 0.f, t1 = 0.f, t2 = 0.f, t3 = 0.f;
#pragma unroll
                for (int nj = 0; nj < 4; ++nj) {
                    const float kv = acc[mi][nj][rr];
                    const int n = nblk + (nj >> 1) * 128 + wc * 32 + (nj & 1) * 16 + l15;
                    const float xv = xq[(size_t)m * N + n];
                    const float q  = (xv - mu) * rx * gqv[nj] + bqv[nj];
                    const float qg = q * gkv[nj];
                    s1 += kv; s2 += kv * kv;
                    t1 += qg * kv; t2 += qg; t3 += q * bkv[nj];
                }
#pragma unroll
                for (int o = 1; o < 16; o <<= 1) {
                    s1 += __shfl_xor(s1, o); s2 += __shfl_xor(s2, o);
                    t1 += __shfl_xor(t1, o); t2 += __shfl_xor(t2, o);
                    t3 += __shfl_xor(t3, o);
                }
                if (l15 == 0) {
                    float* d = red + ((size_t)rloc * 4 + wc) * 5;
                    d[0] = s1; d[1] = s2; d[2] = t1; d[3] = t2; d[4] = t3;
                }
            }
        }
        BAR();
        const int nb = nblk >> 8;
        for (int e = tid; e < 1280; e += 512) {
            const int row = e / 5, v = e - row * 5;
            const float s = red[((size_t)row * 4 + 0) * 5 + v] + red[((size_t)row * 4 + 1) * 5 + v]
                          + red[((size_t)row * 4 + 2) * 5 + v] + red[((size_t)row * 4 + 3) * 5 + v];
            partial[((size_t)(mblk + row) * 8 + nb) * 5 + v] = s;
        }
    } else {
        // direct fragment epilogue: D row=(lane>>4)*4+r, col=lane&15
#pragma unroll
        for (int mi = 0; mi < 8; ++mi) {
#pragma unroll
            for (int rr = 0; rr < 4; ++rr) {
                const int m = mblk + (mi >> 2) * 128 + wr * 64 + (mi & 3) * 16 + lhi * 4 + rr;
                const float sc = (EPI == 1) ? rowscale[m] : 1.0f;
#pragma unroll
                for (int nj = 0; nj < 4; ++nj) {
                    const int n = nblk + (nj >> 1) * 128 + wc * 32 + (nj & 1) * 16 + l15;
                    const float v = acc[mi][nj][rr] * sc;
                    if (EPI == 1) ((u16*)Cout)[(size_t)m * N + n] = f2bf(v);
                    else          ((float*)Cout)[(size_t)m * N + n] = v;
                }
            }
        }
    }
}

extern "C" void kernel_launch(void* const* d_in, const int* in_sizes, int n_in,
                              void* d_out, int out_size, void* d_ws, size_t ws_size,
                              hipStream_t stream) {
    const float* x      = (const float*)d_in[0];
    const int*   hashes = (const int*)d_in[1];
    const int*   offs   = (const int*)d_in[2];
    const float* emb    = (const float*)d_in[3];
    const float* conv_w = (const float*)d_in[4];
    const float* lncg   = (const float*)d_in[5];
    const float* lncb   = (const float*)d_in[6];
    const float* Wk     = (const float*)d_in[7];
    const float* Wv     = (const float*)d_in[8];
    const float* Wo     = (const float*)d_in[9];
    const float* lnkg   = (const float*)d_in[10];
    const float* lnkb   = (const float*)d_in[11];
    const float* lnqg   = (const float*)d_in[12];
    const float* lnqb   = (const float*)d_in[13];

    // ws layout (~107 MB): E (16.8, dead after k_conv) aliases value (67, written
    // by GEMM2 later). key is never materialized (fused gamma path).
    char* p = (char*)d_ws;
    float* E     = (float*)p;
    u16*   value = (u16*)p;   p += (size_t)BT_ * HID * 2;   // 67 MB (E fits inside)
    u16*   A3    = (u16*)p;   p += (size_t)BT_ * K3 * 2;    // 25 MB
    u16*   Wk3   = (u16*)p;   p += (size_t)HID * K3 * 2;    // 3 MB
    u16*   Wvb   = (u16*)p;   p += (size_t)HID * ED * 2;    // 1 MB
    u16*   Wob   = (u16*)p;   p += (size_t)HID * HID * 2;   // 8.4 MB
    float* xs    = (float*)p; p += (size_t)BT_ * 2 * 4;     // 128 KB
    float* part  = (float*)p; p += (size_t)BT_ * 8 * 5 * 4; // 2.6 MB
    float* gamma = (float*)p; p += (size_t)BT_ * 4;         // 64 KB

    hipFuncSetAttribute((const void*)gemm8<0>,
                        hipFuncAttributeMaxDynamicSharedMemorySize, 131072);
    hipFuncSetAttribute((const void*)gemm8<1>,
                        hipFuncAttributeMaxDynamicSharedMemorySize, 131072);
    hipFuncSetAttribute((const void*)gemm8<2>,
                        hipFuncAttributeMaxDynamicSharedMemorySize, 131072);

    k_cvt<<<(HID * ED + 255) / 256, 256, 0, stream>>>(Wv, Wvb, HID * ED);
    k_cvt<<<(HID * HID + 255) / 256, 256, 0, stream>>>(Wo, Wob, HID * HID);
    k_cvt_wk3<<<(HID * ED) / 256, 256, 0, stream>>>(Wk, Wk3);
    k_gather<<<BT_, 256, 0, stream>>>(hashes, offs, emb, E);
    k_conv<<<BT_, 256, 0, stream>>>(E, conv_w, lncg, lncb, A3);
    k_xstat<<<BT_, 256, 0, stream>>>(x, xs);

    const dim3 grid((BT_ / 256) * (HID / 256));   // 512 = 64x8 tiles
    // key partials: [ehi|ehi|elo] @ [Wkhi|Wklo|Wkhi]^T (K'=768), reduce in epilogue
    gemm8<2><<<grid, 512, 131072, stream>>>(
        A3, K3, Wk3, K3, nullptr, nullptr, BT_, HID, K3,
        x, xs, lnqg, lnqb, lnkg, lnkb, part);
    k_gamma2<<<BT_ / 256, 256, 0, stream>>>(part, gamma);
    // value = gamma * (ehi @ Wv^T)  (K=256) -> bf16
    gemm8<1><<<grid, 512, 131072, stream>>>(
        A3, K3, Wvb, ED, gamma, value, BT_, HID, ED,
        nullptr, nullptr, nullptr, nullptr, nullptr, nullptr, nullptr);
    // out = value @ Wo^T  (K=2048) -> f32
    gemm8<0><<<grid, 512, 131072, stream>>>(
        value, HID, Wob, HID, nullptr, d_out, BT_, HID, HID,
        nullptr, nullptr, nullptr, nullptr, nullptr, nullptr, nullptr);
}

// Round 11
// 288.222 us; speedup vs baseline: 1.3390x; 1.1749x over previous
//
#include <hip/hip_runtime.h>
#include <stdint.h>
#include <math.h>

#define B_   4
#define T_   4096
#define BT_  16384
#define HID  2048
#define ED   256
#define HD   32
#define NH   8
#define K3   768    // packed split K (hi|hi|lo)
#define KW   6144   // packed split K for W2 = Wo@Wv (hi|hi|lo over 2048)
#define KSP  8      // K-split for W2 GEMM

typedef unsigned short u16;
typedef __attribute__((ext_vector_type(8))) short short8;
typedef __attribute__((ext_vector_type(4))) float f32x4;

typedef __attribute__((address_space(1))) void gvoid;
typedef __attribute__((address_space(3))) void lvoid;

__device__ __forceinline__ float bf2f(u16 h) {
    return __uint_as_float(((uint32_t)h) << 16);
}
__device__ __forceinline__ u16 f2bf(float f) {
    uint32_t u = __float_as_uint(f);
    u += 0x7FFFu + ((u >> 16) & 1u);   // round-to-nearest-even
    return (u16)(u >> 16);
}
__device__ __forceinline__ void gld_lds16(const void* g, void* l) {
    __builtin_amdgcn_global_load_lds((gvoid*)(uintptr_t)g, (lvoid*)(uintptr_t)l, 16, 0, 0);
}
__device__ __forceinline__ void BAR() {
    asm volatile("" ::: "memory");
    __builtin_amdgcn_s_barrier();
    asm volatile("" ::: "memory");
}

// ---- Wk -> packed [hi | lo | hi] rows of 768 (pairs with A3 = [hi | hi | lo]) ----
__global__ void k_cvt_wk3(const float* __restrict__ in, u16* __restrict__ out) {
    int i = blockIdx.x * 256 + threadIdx.x;   // over HID*ED
    int n = i >> 8, c = i & 255;
    float f = in[i];
    u16 h = f2bf(f);
    out[(size_t)n * K3 + c]       = h;
    out[(size_t)n * K3 + 256 + c] = f2bf(f - bf2f(h));
    out[(size_t)n * K3 + 512 + c] = h;
}

// ---- Wo (2048x2048 f32) -> WoP [2048][6144] = [hi | hi | lo] ----
__global__ void k_packWo(const float* __restrict__ wo, u16* __restrict__ wop) {
    int i = blockIdx.x * 256 + threadIdx.x;   // over 2048*2048
    int o = i >> 11, n = i & 2047;
    float f = wo[i];
    u16 h = f2bf(f);
    wop[(size_t)o * KW + n]        = h;
    wop[(size_t)o * KW + 2048 + n] = h;
    wop[(size_t)o * KW + 4096 + n] = f2bf(f - bf2f(h));
}

// ---- Wv (2048x256 f32, row n col c) -> WvP [256][6144] = [hi | lo | hi] (transposed) ----
__global__ void k_packWv(const float* __restrict__ wv, u16* __restrict__ wvp) {
    int i = blockIdx.x * 256 + threadIdx.x;   // over 2048*256
    int n = i >> 8, c = i & 255;
    float f = wv[i];
    u16 h = f2bf(f);
    wvp[(size_t)c * KW + n]        = h;
    wvp[(size_t)c * KW + 2048 + n] = f2bf(f - bf2f(h));
    wvp[(size_t)c * KW + 4096 + n] = h;
}

// ---- reduce 8 K-split partials -> W2 f32 -> W23 [2048][768] = [hi | lo | hi] ----
__global__ void k_w2pack(const float* __restrict__ part, u16* __restrict__ w23) {
    int i = blockIdx.x * 256 + threadIdx.x;   // over 2048*256
    int o = i >> 8, c = i & 255;
    float s = 0.f;
#pragma unroll
    for (int k = 0; k < KSP; ++k) s += part[(size_t)k * HID * ED + i];
    u16 h = f2bf(s);
    w23[(size_t)o * K3 + c]       = h;
    w23[(size_t)o * K3 + 256 + c] = f2bf(s - bf2f(h));
    w23[(size_t)o * K3 + 512 + c] = h;
}

// ---------------- hash-embedding gather (f32) ----------------
__global__ void k_gather(const int* __restrict__ hashes, const int* __restrict__ offs,
                         const float* __restrict__ tab, float* __restrict__ E) {
    const int bt = blockIdx.x;
    const int tid = threadIdx.x;          // 256 = 8 heads x 32 dims
    const int head = tid >> 5, d = tid & 31;
    const int row = hashes[bt * NH + head] + offs[head];
    E[(size_t)bt * ED + tid] = tab[(size_t)row * HD + d];
}

// ---- conv + LN + silu + residual; writes A3 row = [e_hi | e_hi | e_lo] (768) ----
__global__ void k_conv(const float* __restrict__ E, const float* __restrict__ w,
                       const float* __restrict__ lng, const float* __restrict__ lnb,
                       u16* __restrict__ a3) {
    const int bt = blockIdx.x;
    const int b = bt >> 12;               // T_ = 4096
    const int t = bt & 4095;
    const int ch = threadIdx.x;           // 256
    float c = 0.f;
#pragma unroll
    for (int k = 0; k < 4; ++k) {
        int tt = t - 9 + 3 * k;           // taps at t-9, t-6, t-3, t
        if (tt >= 0)
            c += w[ch * 4 + k] * E[((size_t)(b * T_ + tt)) * ED + ch];
    }
    float s = c, s2 = c * c;
#pragma unroll
    for (int o = 32; o; o >>= 1) { s += __shfl_xor(s, o); s2 += __shfl_xor(s2, o); }
    __shared__ float red[8];
    const int wid = ch >> 6, lane = ch & 63;
    if (!lane) { red[wid] = s; red[4 + wid] = s2; }
    __syncthreads();
    s  = red[0] + red[1] + red[2] + red[3];
    s2 = red[4] + red[5] + red[6] + red[7];
    const float mean = s * (1.f / 256.f);
    const float var  = s2 * (1.f / 256.f) - mean * mean;
    float ln = (c - mean) * rsqrtf(var + 1e-5f) * lng[ch] + lnb[ch];
    float si = ln / (1.f + expf(-ln));    // silu
    float ev = E[(size_t)bt * ED + ch] + si;
    u16 h = f2bf(ev);
    a3[(size_t)bt * K3 + ch]       = h;
    a3[(size_t)bt * K3 + 256 + ch] = h;
    a3[(size_t)bt * K3 + 512 + ch] = f2bf(ev - bf2f(h));
}

// ---------------- per-row x stats: mu, rsqrt(var+eps) ----------------
__global__ void k_xstat(const float* __restrict__ x, float* __restrict__ xs) {
    const int m = blockIdx.x;
    const int tid = threadIdx.x;          // 256 thr, 2 float4 each
    const f32x4* xr = (const f32x4*)(x + (size_t)m * HID);
    float sx = 0.f, sx2 = 0.f;
#pragma unroll
    for (int i = 0; i < 2; ++i) {
        f32x4 xv = xr[tid + i * 256];
#pragma unroll
        for (int c = 0; c < 4; ++c) { sx += xv[c]; sx2 += xv[c] * xv[c]; }
    }
#pragma unroll
    for (int o = 32; o; o >>= 1) { sx += __shfl_xor(sx, o); sx2 += __shfl_xor(sx2, o); }
    __shared__ float red[8];
    const int wid = tid >> 6, lane = tid & 63;
    if (!lane) { red[wid] = sx; red[4 + wid] = sx2; }
    __syncthreads();
    if (tid == 0) {
        sx  = red[0] + red[1] + red[2] + red[3];
        sx2 = red[4] + red[5] + red[6] + red[7];
        const float inv = 1.f / (float)HID;
        const float mu = sx * inv, var = sx2 * inv - mu * mu;
        xs[m * 2]     = mu;
        xs[m * 2 + 1] = rsqrtf(var + 1e-5f);
    }
}

// ---------------- finalize gamma from 8 partial slices ----------------
// dot = rk*(T1 - mu_k*T2) + T3 ; partial[m][nb][5] = {S1,S2,T1,T2,T3}
__global__ void k_gamma2(const float* __restrict__ partial, float* __restrict__ gamma) {
    const int m = blockIdx.x * 256 + threadIdx.x;
    float s[5] = {0.f, 0.f, 0.f, 0.f, 0.f};
    const float* p = partial + (size_t)m * 40;
#pragma unroll
    for (int nb = 0; nb < 8; ++nb)
#pragma unroll
        for (int v = 0; v < 5; ++v) s[v] += p[nb * 5 + v];
    const float inv = 1.f / (float)HID;
    const float mu = s[0] * inv, var = s[1] * inv - mu * mu;
    const float rk = rsqrtf(var + 1e-5f);
    const float dot = rk * (s[2] - mu * s[3]) + s[4];
    const float gd = dot * 0.022097086912079608f;   // 1/sqrt(2048)
    const float sg = (gd > 0.f) ? 1.f : ((gd < 0.f) ? -1.f : 0.f);
    const float sv = sqrtf(fmaxf(fabsf(gd), 1e-6f)) * sg;
    gamma[m] = 1.f / (1.f + expf(-sv));
}

// ================= 256x256 / BK=64 bf16 MFMA GEMM — pipelined, chunk-aligned =================
// (r10-validated core: chunk-pure reads, 4-phase staging, vmcnt(6), 0 bank conflicts.)
// GRID=0: 2D XCD chunking, grid MUST be 64x8 tiles (BT x HID shapes).
// GRID=1: plain row-major tile mapping + K-split via blockIdx.y (A,B advance
//         blockIdx.y*K columns; EPI0 output goes to partial slab blockIdx.y).
// EPI: 0 = f32 store (K-split slab); 2 = fused key->gamma partial reduction
//      (key never materialized); 3 = f32 store with rowscale (out = gamma * e@W2^T).
template <int EPI, int GRID>
__global__ __launch_bounds__(512, 2)
void gemm8(const u16* __restrict__ A, int lda, const u16* __restrict__ Bm, int ldb,
           const float* __restrict__ rowscale, void* __restrict__ Cout,
           int M, int N, int K,
           const float* __restrict__ xq, const float* __restrict__ xs,
           const float* __restrict__ gq, const float* __restrict__ bq,
           const float* __restrict__ gk, const float* __restrict__ bk,
           float* __restrict__ partial) {
    extern __shared__ char smem[];
    const int tid = threadIdx.x, wid = tid >> 6, lane = tid & 63;
    const int l15 = lane & 15, lhi = lane >> 4;
    const int wr = wid >> 2, wc = wid & 3;

    const int id = blockIdx.x;
    int mblk, nblk;
    if (GRID == 0) {
        // 2D XCD chunking: xcd = id&7 owns an 8(m) x 8(n) tile chunk
        const int xcd = id & 7, loc = id >> 3;
        mblk = ((xcd << 3) + (loc & 7)) << 8;
        nblk = (loc >> 3) << 8;
    } else {
        const int tiles_m = M >> 8;
        mblk = (id % tiles_m) << 8;
        nblk = (id / tiles_m) << 8;
        const size_t koff = (size_t)blockIdx.y * K;
        A  += koff;
        Bm += koff;
    }

    f32x4 acc[8][4];
#pragma unroll
    for (int i = 0; i < 8; ++i)
#pragma unroll
        for (int j = 0; j < 4; ++j) acc[i][j] = f32x4{0.f, 0.f, 0.f, 0.f};

    const int srow = tid >> 3;
    const int scol = ((tid & 7) << 3) ^ ((srow & 7) << 3);
    const u16* aS[4];
    const u16* bS[4];
#pragma unroll
    for (int h = 0; h < 2; ++h)
#pragma unroll
        for (int r = 0; r < 2; ++r) {
            aS[h * 2 + r] = A  + (size_t)(mblk + h * 128 + r * 64 + srow) * lda + scol;
            bS[h * 2 + r] = Bm + (size_t)(nblk + h * 128 + r * 64 + srow) * ldb + scol;
        }
    const int wb = wid * 1024;

    const int koff0 = (lhi * 16) ^ ((l15 & 7) << 4);
    const int koff1 = (64 + lhi * 16) ^ ((l15 & 7) << 4);

    short8 ar[4][2], br[2][2][2];

#define SA(h, tt) do { const int kk_ = (tt) << 6;                                    \
        char* d_ = smem + (((tt) & 1) * 32768) + (h) * 16384 + wb;                   \
        gld_lds16(aS[(h) * 2 + 0] + kk_, d_);                                        \
        gld_lds16(aS[(h) * 2 + 1] + kk_, d_ + 8192); } while (0)
#define SB(h, tt) do { const int kk_ = (tt) << 6;                                    \
        char* d_ = smem + 65536 + (((tt) & 1) * 32768) + (h) * 16384 + wb;           \
        gld_lds16(bS[(h) * 2 + 0] + kk_, d_);                                        \
        gld_lds16(bS[(h) * 2 + 1] + kk_, d_ + 8192); } while (0)
#define LDA_SUB(mh, p) do {                                                          \
        const char* ab_ = smem + (p) * 32768 + ((mh) * 128 + wr * 64) * 128;         \
        _Pragma("unroll") for (int fm = 0; fm < 4; ++fm) {                           \
            const char* rb_ = ab_ + (fm * 16 + l15) * 128;                           \
            ar[fm][0] = *(const short8*)(rb_ + koff0);                               \
            ar[fm][1] = *(const short8*)(rb_ + koff1); } } while (0)
#define LDB_SUB(nh, p) do {                                                          \
        const char* bb_ = smem + 65536 + (p) * 32768 + ((nh) * 128 + wc * 32) * 128; \
        _Pragma("unroll") for (int fn = 0; fn < 2; ++fn) {                           \
            const char* rb_ = bb_ + (fn * 16 + l15) * 128;                           \
            br[nh][fn][0] = *(const short8*)(rb_ + koff0);                           \
            br[nh][fn][1] = *(const short8*)(rb_ + koff1); } } while (0)
#define MMQ(mh, nh) do { __builtin_amdgcn_s_setprio(1);                              \
        _Pragma("unroll") for (int fm = 0; fm < 4; ++fm)                             \
        _Pragma("unroll") for (int fn = 0; fn < 2; ++fn) {                           \
            acc[(mh) * 4 + fm][(nh) * 2 + fn] = __builtin_amdgcn_mfma_f32_16x16x32_bf16( \
                ar[fm][0], br[nh][fn][0], acc[(mh) * 4 + fm][(nh) * 2 + fn], 0, 0, 0);   \
            acc[(mh) * 4 + fm][(nh) * 2 + fn] = __builtin_amdgcn_mfma_f32_16x16x32_bf16( \
                ar[fm][1], br[nh][fn][1], acc[(mh) * 4 + fm][(nh) * 2 + fn], 0, 0, 0); } \
        __builtin_amdgcn_s_setprio(0); } while (0)

    // prologue: tiles 0,1 fully staged (16 loads); drain tile 0 (oldest 8)
    SA(0, 0); SA(1, 0); SB(0, 0); SB(1, 0);
    SA(0, 1); SA(1, 1); SB(0, 1); SB(1, 1);
    asm volatile("s_waitcnt vmcnt(8)" ::: "memory");
    BAR();

    const int nk = K >> 6;
    for (int t = 0; t < nk; ++t) {
        const int p = t & 1;
        // P1: reads Ah0,Bh0 of buf p; stage Ah1(t+1) -> p^1 (freed (t-1).P3)
        LDA_SUB(0, p); LDB_SUB(0, p);
        if (t >= 1 && t + 1 < nk) SA(1, t + 1);
        BAR(); MMQ(0, 0); BAR();
        // P2: reads Bh1; stage Ah0(t+2) -> p (region freed at P1)
        LDB_SUB(1, p);
        if (t + 2 < nk) SA(0, t + 2);
        BAR(); MMQ(0, 1); BAR();
        // P3: reads Ah1; stage Bh0(t+2) -> p (freed at P1)
        LDA_SUB(1, p);
        if (t + 2 < nk) SB(0, t + 2);
        BAR(); MMQ(1, 0); BAR();
        // P4: regs only; stage Bh1(t+2) -> p (freed at P2); vmcnt(6) leaves the
        // 3 halves staged this tile, drains all of t+1
        if (t + 2 < nk) {
            SB(1, t + 2);
            asm volatile("s_waitcnt vmcnt(6)" ::: "memory");
        } else {
            asm volatile("s_waitcnt vmcnt(0)" ::: "memory");
        }
        BAR(); MMQ(1, 1); BAR();
    }
#undef SA
#undef SB
#undef LDA_SUB
#undef LDB_SUB
#undef MMQ

    if (EPI == 2) {
        // ---- fused key->gamma partial reduction (key stays in registers) ----
        float gqv[4], bqv[4], gkv[4], bkv[4];
#pragma unroll
        for (int nj = 0; nj < 4; ++nj) {
            const int n = nblk + (nj >> 1) * 128 + wc * 32 + (nj & 1) * 16 + l15;
            gqv[nj] = gq[n]; bqv[nj] = bq[n]; gkv[nj] = gk[n]; bkv[nj] = bk[n];
        }
        float* red = (float*)smem;           // [256 rows][4 wc][5] = 20 KB
#pragma unroll
        for (int mi = 0; mi < 8; ++mi) {
#pragma unroll
            for (int rr = 0; rr < 4; ++rr) {
                const int rloc = (mi >> 2) * 128 + wr * 64 + (mi & 3) * 16 + lhi * 4 + rr;
                const int m = mblk + rloc;
                const float mu = xs[m * 2], rx = xs[m * 2 + 1];
                float s1 = 0.f, s2 = 0.f, t1 = 0.f, t2 = 0.f, t3 = 0.f;
#pragma unroll
                for (int nj = 0; nj < 4; ++nj) {
                    const float kv = acc[mi][nj][rr];
                    const int n = nblk + (nj >> 1) * 128 + wc * 32 + (nj & 1) * 16 + l15;
                    const float xv = xq[(size_t)m * N + n];
                    const float q  = (xv - mu) * rx * gqv[nj] + bqv[nj];
                    const float qg = q * gkv[nj];
                    s1 += kv; s2 += kv * kv;
                    t1 += qg * kv; t2 += qg; t3 += q * bkv[nj];
                }
#pragma unroll
                for (int o = 1; o < 16; o <<= 1) {
                    s1 += __shfl_xor(s1, o); s2 += __shfl_xor(s2, o);
                    t1 += __shfl_xor(t1, o); t2 += __shfl_xor(t2, o);
                    t3 += __shfl_xor(t3, o);
                }
                if (l15 == 0) {
                    float* d = red + ((size_t)rloc * 4 + wc) * 5;
                    d[0] = s1; d[1] = s2; d[2] = t1; d[3] = t2; d[4] = t3;
                }
            }
        }
        BAR();
        const int nb = nblk >> 8;
        for (int e = tid; e < 1280; e += 512) {
            const int row = e / 5, v = e - row * 5;
            const float s = red[((size_t)row * 4 + 0) * 5 + v] + red[((size_t)row * 4 + 1) * 5 + v]
                          + red[((size_t)row * 4 + 2) * 5 + v] + red[((size_t)row * 4 + 3) * 5 + v];
            partial[((size_t)(mblk + row) * 8 + nb) * 5 + v] = s;
        }
    } else {
        // direct fragment epilogue: D row=(lane>>4)*4+r, col=lane&15
        float* Cf = (float*)Cout;
        if (EPI == 0 && GRID == 1) Cf += (size_t)blockIdx.y * M * N;   // K-split slab
#pragma unroll
        for (int mi = 0; mi < 8; ++mi) {
#pragma unroll
            for (int rr = 0; rr < 4; ++rr) {
                const int m = mblk + (mi >> 2) * 128 + wr * 64 + (mi & 3) * 16 + lhi * 4 + rr;
                const float sc = (EPI == 3) ? rowscale[m] : 1.0f;
#pragma unroll
                for (int nj = 0; nj < 4; ++nj) {
                    const int n = nblk + (nj >> 1) * 128 + wc * 32 + (nj & 1) * 16 + l15;
                    Cf[(size_t)m * N + n] = acc[mi][nj][rr] * sc;
                }
            }
        }
    }
}

extern "C" void kernel_launch(void* const* d_in, const int* in_sizes, int n_in,
                              void* d_out, int out_size, void* d_ws, size_t ws_size,
                              hipStream_t stream) {
    const float* x      = (const float*)d_in[0];
    const int*   hashes = (const int*)d_in[1];
    const int*   offs   = (const int*)d_in[2];
    const float* emb    = (const float*)d_in[3];
    const float* conv_w = (const float*)d_in[4];
    const float* lncg   = (const float*)d_in[5];
    const float* lncb   = (const float*)d_in[6];
    const float* Wk     = (const float*)d_in[7];
    const float* Wv     = (const float*)d_in[8];
    const float* Wo     = (const float*)d_in[9];
    const float* lnkg   = (const float*)d_in[10];
    const float* lnkb   = (const float*)d_in[11];
    const float* lnqg   = (const float*)d_in[12];
    const float* lnqb   = (const float*)d_in[13];

    // ws (~80 MB). E (16.8MB, dead after k_conv) aliases W2part (16.8MB, written
    // by the W2 K-split GEMM afterwards). key/value never materialized:
    // out = gamma * (e @ (Wo@Wv)^T)  [gamma folds through the row-diagonal].
    char* p = (char*)d_ws;
    float* E      = (float*)p;
    float* W2part = (float*)p;  p += (size_t)KSP * HID * ED * 4;  // 16.8 MB (== BT*ED*4)
    u16*   A3     = (u16*)p;    p += (size_t)BT_ * K3 * 2;        // 25.2 MB
    u16*   Wk3    = (u16*)p;    p += (size_t)HID * K3 * 2;        // 3.1 MB
    u16*   WoP    = (u16*)p;    p += (size_t)HID * KW * 2;        // 25.2 MB
    u16*   WvP    = (u16*)p;    p += (size_t)ED * KW * 2;         // 3.1 MB
    u16*   W23    = (u16*)p;    p += (size_t)HID * K3 * 2;        // 3.1 MB
    float* xs     = (float*)p;  p += (size_t)BT_ * 2 * 4;         // 128 KB
    float* part   = (float*)p;  p += (size_t)BT_ * 8 * 5 * 4;     // 2.6 MB
    float* gamma  = (float*)p;  p += (size_t)BT_ * 4;             // 64 KB

    hipFuncSetAttribute((const void*)gemm8<0, 1>,
                        hipFuncAttributeMaxDynamicSharedMemorySize, 131072);
    hipFuncSetAttribute((const void*)gemm8<2, 0>,
                        hipFuncAttributeMaxDynamicSharedMemorySize, 131072);
    hipFuncSetAttribute((const void*)gemm8<3, 0>,
                        hipFuncAttributeMaxDynamicSharedMemorySize, 131072);

    k_cvt_wk3<<<(HID * ED) / 256, 256, 0, stream>>>(Wk, Wk3);
    k_packWo<<<(HID * HID) / 256, 256, 0, stream>>>(Wo, WoP);
    k_packWv<<<(HID * ED) / 256, 256, 0, stream>>>(Wv, WvP);
    k_gather<<<BT_, 256, 0, stream>>>(hashes, offs, emb, E);
    k_conv<<<BT_, 256, 0, stream>>>(E, conv_w, lncg, lncb, A3);
    k_xstat<<<BT_, 256, 0, stream>>>(x, xs);

    // W2 = Wo @ Wv in split precision: WoP [2048][6144] x WvP [256][6144],
    // K-split 8 x 768 via blockIdx.y -> f32 partial slabs (over dead E).
    gemm8<0, 1><<<dim3(HID / 256, KSP), 512, 131072, stream>>>(
        WoP, KW, WvP, KW, nullptr, W2part, HID, ED, KW / KSP,
        nullptr, nullptr, nullptr, nullptr, nullptr, nullptr, nullptr);
    k_w2pack<<<(HID * ED) / 256, 256, 0, stream>>>(W2part, W23);

    const dim3 grid((BT_ / 256) * (HID / 256));   // 512 = 64x8 tiles
    // key partials: A3 @ Wk3^T (K=768), gamma reduction fused in epilogue
    gemm8<2, 0><<<grid, 512, 131072, stream>>>(
        A3, K3, Wk3, K3, nullptr, nullptr, BT_, HID, K3,
        x, xs, lnqg, lnqb, lnkg, lnkb, part);
    k_gamma2<<<BT_ / 256, 256, 0, stream>>>(part, gamma);
    // out = gamma * (A3 @ W23^T)  (K=768) -> d_out f32
    gemm8<3, 0><<<grid, 512, 131072, stream>>>(
        A3, K3, W23, K3, gamma, d_out, BT_, HID, K3,
        nullptr, nullptr, nullptr, nullptr, nullptr, nullptr, nullptr);
}